// Round 1
// baseline (929.615 us; speedup 1.0000x reference)
//
#include <hip/hip_runtime.h>
#include <hip/hip_bf16.h>

#define IN_C 256
#define C1   128   // HEADS*HID
#define OUT_CH 64
#define NEG 0.2f

__device__ __forceinline__ float leaky(float x) { return x > 0.f ? x : NEG * x; }

// ---------------- GEMM1: [M,256] x [256,128] -> [M,128] ----------------
__global__ __launch_bounds__(256) void k_gemm1(const float* __restrict__ X,
                                               const float* __restrict__ W,
                                               float* __restrict__ H, int M)
{
    __shared__ float As[32][68];   // transposed [k][m], +4 pad keeps rows 16B-aligned
    __shared__ float Bs[32][128];
    const int tid = threadIdx.x;
    const int rowBase = blockIdx.x * 64;
    const int tr = tid >> 5;       // 0..7  -> rows tr*8 .. tr*8+7
    const int tc = tid & 31;       // 0..31 -> cols tc*4 .. tc*4+3
    float acc[8][4];
#pragma unroll
    for (int i = 0; i < 8; ++i)
#pragma unroll
        for (int j = 0; j < 4; ++j) acc[i][j] = 0.f;

    for (int k0 = 0; k0 < 256; k0 += 32) {
#pragma unroll
        for (int i = 0; i < 2; ++i) {
            int q = tid + i * 256;
            int m = q >> 3, k4 = (q & 7) << 2;
            int r = rowBase + m; if (r > M - 1) r = M - 1;
            float4 v = *(const float4*)(X + (size_t)r * IN_C + k0 + k4);
            As[k4 + 0][m] = v.x; As[k4 + 1][m] = v.y;
            As[k4 + 2][m] = v.z; As[k4 + 3][m] = v.w;
        }
#pragma unroll
        for (int i = 0; i < 4; ++i) {
            int q = tid + i * 256;
            int kk = q >> 5, c4 = (q & 31) << 2;
            *(float4*)(&Bs[kk][c4]) = *(const float4*)(W + (size_t)(k0 + kk) * C1 + c4);
        }
        __syncthreads();
#pragma unroll
        for (int k = 0; k < 32; ++k) {
            float4 a0 = *(const float4*)(&As[k][tr * 8]);
            float4 a1 = *(const float4*)(&As[k][tr * 8 + 4]);
            float4 b  = *(const float4*)(&Bs[k][tc * 4]);
            float av[8] = {a0.x, a0.y, a0.z, a0.w, a1.x, a1.y, a1.z, a1.w};
            float bv[4] = {b.x, b.y, b.z, b.w};
#pragma unroll
            for (int i = 0; i < 8; ++i)
#pragma unroll
                for (int j = 0; j < 4; ++j) acc[i][j] = fmaf(av[i], bv[j], acc[i][j]);
        }
        __syncthreads();
    }
#pragma unroll
    for (int i = 0; i < 8; ++i) {
        int r = rowBase + tr * 8 + i;
        if (r < M) {
            float4 v = {acc[i][0], acc[i][1], acc[i][2], acc[i][3]};
            *(float4*)(H + (size_t)r * C1 + tc * 4) = v;
        }
    }
}

// ---------------- GEMM2: [M,128] x [128,64] -> [M,64] ----------------
__global__ __launch_bounds__(256) void k_gemm2(const float* __restrict__ X,
                                               const float* __restrict__ W,
                                               float* __restrict__ H, int M)
{
    __shared__ float As[32][132];  // [k][m], BM=128, +4 pad
    __shared__ float Bs[32][64];
    const int tid = threadIdx.x;
    const int rowBase = blockIdx.x * 128;
    const int tr = tid >> 4;       // 0..15 -> rows tr*8
    const int tc = tid & 15;       // 0..15 -> cols tc*4
    float acc[8][4];
#pragma unroll
    for (int i = 0; i < 8; ++i)
#pragma unroll
        for (int j = 0; j < 4; ++j) acc[i][j] = 0.f;

    for (int k0 = 0; k0 < 128; k0 += 32) {
#pragma unroll
        for (int i = 0; i < 4; ++i) {
            int q = tid + i * 256;
            int m = q >> 3, k4 = (q & 7) << 2;
            int r = rowBase + m; if (r > M - 1) r = M - 1;
            float4 v = *(const float4*)(X + (size_t)r * C1 + k0 + k4);
            As[k4 + 0][m] = v.x; As[k4 + 1][m] = v.y;
            As[k4 + 2][m] = v.z; As[k4 + 3][m] = v.w;
        }
#pragma unroll
        for (int i = 0; i < 2; ++i) {
            int q = tid + i * 256;
            int kk = q >> 4, c4 = (q & 15) << 2;
            *(float4*)(&Bs[kk][c4]) = *(const float4*)(W + (size_t)(k0 + kk) * OUT_CH + c4);
        }
        __syncthreads();
#pragma unroll
        for (int k = 0; k < 32; ++k) {
            float4 a0 = *(const float4*)(&As[k][tr * 8]);
            float4 a1 = *(const float4*)(&As[k][tr * 8 + 4]);
            float4 b  = *(const float4*)(&Bs[k][tc * 4]);
            float av[8] = {a0.x, a0.y, a0.z, a0.w, a1.x, a1.y, a1.z, a1.w};
            float bv[4] = {b.x, b.y, b.z, b.w};
#pragma unroll
            for (int i = 0; i < 8; ++i)
#pragma unroll
                for (int j = 0; j < 4; ++j) acc[i][j] = fmaf(av[i], bv[j], acc[i][j]);
        }
        __syncthreads();
    }
#pragma unroll
    for (int i = 0; i < 8; ++i) {
        int r = rowBase + tr * 8 + i;
        if (r < M) {
            float4 v = {acc[i][0], acc[i][1], acc[i][2], acc[i][3]};
            *(float4*)(H + (size_t)r * OUT_CH + tc * 4) = v;
        }
    }
}

// ------------- per-node attention logits, layer 1: [N,128] -> [N,8] x2 -------------
__global__ __launch_bounds__(256) void k_att1(const float* __restrict__ H,
                                              const float* __restrict__ atts,
                                              const float* __restrict__ attd,
                                              float* __restrict__ as1,
                                              float* __restrict__ ad1, int N)
{
    int gw = (blockIdx.x * 256 + threadIdx.x) >> 6;
    int lane = threadIdx.x & 63;
    if (gw >= N) return;
    int c0 = lane, c1 = lane + 64;
    float v0 = H[(size_t)gw * C1 + c0], v1 = H[(size_t)gw * C1 + c1];
    float s0 = v0 * atts[c0], s1 = v1 * atts[c1];
    float d0 = v0 * attd[c0], d1 = v1 * attd[c1];
#pragma unroll
    for (int d = 1; d < 16; d <<= 1) {
        s0 += __shfl_xor(s0, d); s1 += __shfl_xor(s1, d);
        d0 += __shfl_xor(d0, d); d1 += __shfl_xor(d1, d);
    }
    if ((lane & 15) == 0) {
        int g = lane >> 4;
        as1[gw * 8 + g]     = s0; as1[gw * 8 + 4 + g] = s1;
        ad1[gw * 8 + g]     = d0; ad1[gw * 8 + 4 + g] = d1;
    }
}

// ------------- per-node attention logits, layer 2: [N,64] -> [N] x2 -------------
__global__ __launch_bounds__(256) void k_att2(const float* __restrict__ H,
                                              const float* __restrict__ atts,
                                              const float* __restrict__ attd,
                                              float* __restrict__ as2,
                                              float* __restrict__ ad2, int N)
{
    int gw = (blockIdx.x * 256 + threadIdx.x) >> 6;
    int lane = threadIdx.x & 63;
    if (gw >= N) return;
    float v = H[(size_t)gw * OUT_CH + lane];
    float s = v * atts[lane], d = v * attd[lane];
#pragma unroll
    for (int k = 1; k < 64; k <<= 1) { s += __shfl_xor(s, k); d += __shfl_xor(d, k); }
    if (lane == 0) { as2[gw] = s; ad2[gw] = d; }
}

// ---------------- CSR build ----------------
__global__ void k_hist(const int* __restrict__ ei, int* __restrict__ counts, int E, int NE)
{
    int e = blockIdx.x * blockDim.x + threadIdx.x;
    if (e >= NE) return;
    int d = (e < E) ? ei[E + e] : (e - E);
    atomicAdd(&counts[d], 1);
}

__global__ __launch_bounds__(1024) void k_bsum(const int* __restrict__ counts,
                                               int* __restrict__ bsums, int n)
{
    __shared__ int sm[1024];
    int tid = threadIdx.x;
    int i = blockIdx.x * 1024 + tid;
    sm[tid] = (i < n) ? counts[i] : 0;
    __syncthreads();
    for (int s = 512; s > 0; s >>= 1) {
        if (tid < s) sm[tid] += sm[tid + s];
        __syncthreads();
    }
    if (tid == 0) bsums[blockIdx.x] = sm[0];
}

__global__ __launch_bounds__(1024) void k_scan_bsums(int* __restrict__ bsums,
                                                     int* __restrict__ offs,
                                                     int nblk, int total, int n)
{
    __shared__ int sm[1024];
    int tid = threadIdx.x;
    int val = (tid < nblk) ? bsums[tid] : 0;
    sm[tid] = val;
    __syncthreads();
    for (int off = 1; off < 1024; off <<= 1) {
        int t = (tid >= off) ? sm[tid - off] : 0;
        __syncthreads();
        sm[tid] += t;
        __syncthreads();
    }
    if (tid < nblk) bsums[tid] = sm[tid] - val;   // exclusive
    if (tid == 0) offs[n] = total;
}

__global__ __launch_bounds__(1024) void k_scan_final(const int* __restrict__ counts,
                                                     const int* __restrict__ bsums,
                                                     int* __restrict__ offs, int n)
{
    __shared__ int sm[1024];
    int tid = threadIdx.x;
    int i = blockIdx.x * 1024 + tid;
    int v = (i < n) ? counts[i] : 0;
    sm[tid] = v;
    __syncthreads();
    for (int off = 1; off < 1024; off <<= 1) {
        int t = (tid >= off) ? sm[tid - off] : 0;
        __syncthreads();
        sm[tid] += t;
        __syncthreads();
    }
    if (i < n) offs[i] = bsums[blockIdx.x] + sm[tid] - v;  // exclusive + block offset
}

__global__ void k_scatter(const int* __restrict__ ei, const int* __restrict__ offs,
                          int* __restrict__ cursor, int* __restrict__ csr, int E, int NE)
{
    int e = blockIdx.x * blockDim.x + threadIdx.x;
    if (e >= NE) return;
    int s, d;
    if (e < E) { s = ei[e]; d = ei[E + e]; } else { s = d = e - E; }
    int pos = offs[d] + atomicAdd(&cursor[d], 1);
    csr[pos] = s;
}

// ------------- layer-1 softmax + aggregate + bias + ELU: one wave per dst node -------------
__global__ __launch_bounds__(256) void k_agg1(const float* __restrict__ H,
                                              const float* __restrict__ as1,
                                              const float* __restrict__ ad1,
                                              const int* __restrict__ offs,
                                              const int* __restrict__ csr,
                                              const float* __restrict__ bias,
                                              float* __restrict__ Hout, int N)
{
    int i = (blockIdx.x * 256 + threadIdx.x) >> 6;
    int lane = threadIdx.x & 63;
    if (i >= N) return;
    const int c0 = lane, c1 = lane + 64;
    const int h0 = lane >> 4, h1h = h0 + 4;
    const int beg = offs[i], end = offs[i + 1];
    const float adv0 = ad1[i * 8 + h0], adv1 = ad1[i * 8 + h1h];

    float m0 = -1e30f, m1 = -1e30f;
    for (int k = beg; k < end; ++k) {
        int j = __builtin_amdgcn_readfirstlane(csr[k]);
        float l0 = leaky(as1[j * 8 + h0]  + adv0);
        float l1 = leaky(as1[j * 8 + h1h] + adv1);
        m0 = fmaxf(m0, l0); m1 = fmaxf(m1, l1);
    }
    float acc0 = 0.f, acc1 = 0.f, den0 = 0.f, den1 = 0.f;
    for (int k = beg; k < end; ++k) {
        int j = __builtin_amdgcn_readfirstlane(csr[k]);
        float l0 = leaky(as1[j * 8 + h0]  + adv0);
        float l1 = leaky(as1[j * 8 + h1h] + adv1);
        float w0 = __expf(l0 - m0), w1 = __expf(l1 - m1);
        acc0 = fmaf(w0, H[(size_t)j * C1 + c0], acc0);
        acc1 = fmaf(w1, H[(size_t)j * C1 + c1], acc1);
        den0 += w0; den1 += w1;
    }
    float o0 = acc0 / (den0 + 1e-16f) + bias[c0];
    float o1 = acc1 / (den1 + 1e-16f) + bias[c1];
    o0 = o0 > 0.f ? o0 : expm1f(o0);   // ELU
    o1 = o1 > 0.f ? o1 : expm1f(o1);
    Hout[(size_t)i * C1 + c0] = o0;
    Hout[(size_t)i * C1 + c1] = o1;
}

// ------------- layer-2 softmax + aggregate + bias + log_softmax -------------
__global__ __launch_bounds__(256) void k_agg2(const float* __restrict__ H,
                                              const float* __restrict__ as2,
                                              const float* __restrict__ ad2,
                                              const int* __restrict__ offs,
                                              const int* __restrict__ csr,
                                              const float* __restrict__ bias,
                                              float* __restrict__ out, int N)
{
    int i = (blockIdx.x * 256 + threadIdx.x) >> 6;
    int lane = threadIdx.x & 63;
    if (i >= N) return;
    const int beg = offs[i], end = offs[i + 1];
    const float adv = ad2[i];

    float m = -1e30f;
    for (int k = beg; k < end; ++k) {
        int j = __builtin_amdgcn_readfirstlane(csr[k]);
        m = fmaxf(m, leaky(as2[j] + adv));
    }
    float acc = 0.f, den = 0.f;
    for (int k = beg; k < end; ++k) {
        int j = __builtin_amdgcn_readfirstlane(csr[k]);
        float w = __expf(leaky(as2[j] + adv) - m);
        acc = fmaf(w, H[(size_t)j * OUT_CH + lane], acc);
        den += w;
    }
    float o = acc / (den + 1e-16f) + bias[lane];
    // log_softmax across the 64 lanes (= 64 channels)
    float mx = o;
#pragma unroll
    for (int k = 1; k < 64; k <<= 1) mx = fmaxf(mx, __shfl_xor(mx, k));
    float ex = __expf(o - mx), s = ex;
#pragma unroll
    for (int k = 1; k < 64; k <<= 1) s += __shfl_xor(s, k);
    out[(size_t)i * OUT_CH + lane] = (o - mx) - logf(s);
}

extern "C" void kernel_launch(void* const* d_in, const int* in_sizes, int n_in,
                              void* d_out, int out_size, void* d_ws, size_t ws_size,
                              hipStream_t stream)
{
    const float* x    = (const float*)d_in[0];
    const int*   ei   = (const int*)  d_in[1];
    const float* W1   = (const float*)d_in[2];
    const float* atS1 = (const float*)d_in[3];
    const float* atD1 = (const float*)d_in[4];
    const float* b1   = (const float*)d_in[5];
    const float* W2   = (const float*)d_in[6];
    const float* atS2 = (const float*)d_in[7];
    const float* atD2 = (const float*)d_in[8];
    const float* b2   = (const float*)d_in[9];
    float* out = (float*)d_out;

    const int N  = in_sizes[0] / IN_C;
    const int E  = in_sizes[1] / 2;
    const int NE = E + N;

    // ---- workspace layout (all f32/int32, ~118 MB) ----
    float* ws   = (float*)d_ws;
    float* h1   = ws;                         // N*128   (reused as h2 after agg1)
    float* hout = h1 + (size_t)N * C1;        // N*128
    float* as1  = hout + (size_t)N * C1;      // N*8
    float* ad1  = as1 + (size_t)N * 8;        // N*8
    float* as2  = ad1 + (size_t)N * 8;        // N
    float* ad2  = as2 + N;                    // N
    int* counts = (int*)(ad2 + N);            // N
    int* offs   = counts + N;                 // N+1
    int* cursor = offs + N + 1;               // N
    int* bsums  = cursor + N;                 // 1024
    int* csr    = bsums + 1024;               // NE
    float* h2   = h1;                         // alias (h1 dead after agg1)

    const int nblk = (N + 1023) / 1024;

    // zero counts + offs + cursor (contiguous: 3N+1 ints)
    hipMemsetAsync(counts, 0, sizeof(int) * (size_t)(3 * N + 1), stream);

    // layer 1 GEMM + logits
    k_gemm1<<<(N + 63) / 64, 256, 0, stream>>>(x, W1, h1, N);
    k_att1<<<(N + 3) / 4, 256, 0, stream>>>(h1, atS1, atD1, as1, ad1, N);

    // CSR build (shared by both layers)
    k_hist<<<(NE + 255) / 256, 256, 0, stream>>>(ei, counts, E, NE);
    k_bsum<<<nblk, 1024, 0, stream>>>(counts, bsums, N);
    k_scan_bsums<<<1, 1024, 0, stream>>>(bsums, offs, nblk, NE, N);
    k_scan_final<<<nblk, 1024, 0, stream>>>(counts, bsums, offs, N);
    k_scatter<<<(NE + 255) / 256, 256, 0, stream>>>(ei, offs, cursor, csr, E, NE);

    // layer 1 aggregate (+bias+ELU)
    k_agg1<<<(N + 3) / 4, 256, 0, stream>>>(h1, as1, ad1, offs, csr, b1, hout, N);

    // layer 2
    k_gemm2<<<(N + 127) / 128, 256, 0, stream>>>(hout, W2, h2, N);
    k_att2<<<(N + 3) / 4, 256, 0, stream>>>(h2, atS2, atD2, as2, ad2, N);
    k_agg2<<<(N + 3) / 4, 256, 0, stream>>>(h2, as2, ad2, offs, csr, b2, out, N);
}

// Round 2
// 505.804 us; speedup vs baseline: 1.8379x; 1.8379x over previous
//
#include <hip/hip_runtime.h>
#include <hip/hip_bf16.h>

#define IN_C 256
#define C1   128   // HEADS*HID
#define OUT_CH 64
#define NEG 0.2f

__device__ __forceinline__ float leaky(float x) { return x > 0.f ? x : NEG * x; }
__device__ __forceinline__ unsigned short f2bf(float f) {
    unsigned int x = __float_as_uint(f);
    unsigned int r = (x + 0x7fffu + ((x >> 16) & 1u)) >> 16;   // RNE
    return (unsigned short)r;
}
__device__ __forceinline__ float bflo(unsigned int v) { return __uint_as_float(v << 16); }
__device__ __forceinline__ float bfhi(unsigned int v) { return __uint_as_float(v & 0xffff0000u); }

// ---------------- GEMM1: [M,256] x [256,128] -> bf16 [M,128] ----------------
__global__ __launch_bounds__(256) void k_gemm1(const float* __restrict__ X,
                                               const float* __restrict__ W,
                                               unsigned short* __restrict__ Hb, int M)
{
    __shared__ float As[32][68];   // transposed [k][m]
    __shared__ float Bs[32][128];
    const int tid = threadIdx.x;
    const int rowBase = blockIdx.x * 64;
    const int tr = tid >> 5;       // 0..7
    const int tc = tid & 31;       // 0..31
    float acc[8][4];
#pragma unroll
    for (int i = 0; i < 8; ++i)
#pragma unroll
        for (int j = 0; j < 4; ++j) acc[i][j] = 0.f;

    for (int k0 = 0; k0 < 256; k0 += 32) {
#pragma unroll
        for (int i = 0; i < 2; ++i) {
            int q = tid + i * 256;
            int m = q >> 3, k4 = (q & 7) << 2;
            int r = rowBase + m; if (r > M - 1) r = M - 1;
            float4 v = *(const float4*)(X + (size_t)r * IN_C + k0 + k4);
            As[k4 + 0][m] = v.x; As[k4 + 1][m] = v.y;
            As[k4 + 2][m] = v.z; As[k4 + 3][m] = v.w;
        }
#pragma unroll
        for (int i = 0; i < 4; ++i) {
            int q = tid + i * 256;
            int kk = q >> 5, c4 = (q & 31) << 2;
            *(float4*)(&Bs[kk][c4]) = *(const float4*)(W + (size_t)(k0 + kk) * C1 + c4);
        }
        __syncthreads();
#pragma unroll
        for (int k = 0; k < 32; ++k) {
            float4 a0 = *(const float4*)(&As[k][tr * 8]);
            float4 a1 = *(const float4*)(&As[k][tr * 8 + 4]);
            float4 b  = *(const float4*)(&Bs[k][tc * 4]);
            float av[8] = {a0.x, a0.y, a0.z, a0.w, a1.x, a1.y, a1.z, a1.w};
            float bv[4] = {b.x, b.y, b.z, b.w};
#pragma unroll
            for (int i = 0; i < 8; ++i)
#pragma unroll
                for (int j = 0; j < 4; ++j) acc[i][j] = fmaf(av[i], bv[j], acc[i][j]);
        }
        __syncthreads();
    }
#pragma unroll
    for (int i = 0; i < 8; ++i) {
        int r = rowBase + tr * 8 + i;
        if (r < M) {
            uint2 v;
            v.x = (unsigned int)f2bf(acc[i][0]) | ((unsigned int)f2bf(acc[i][1]) << 16);
            v.y = (unsigned int)f2bf(acc[i][2]) | ((unsigned int)f2bf(acc[i][3]) << 16);
            *(uint2*)(Hb + (size_t)r * C1 + tc * 4) = v;
        }
    }
}

// ---------------- GEMM2: [M,128] x [128,64] -> bf16 [M,64] ----------------
__global__ __launch_bounds__(256) void k_gemm2(const float* __restrict__ X,
                                               const float* __restrict__ W,
                                               unsigned short* __restrict__ Hb, int M)
{
    __shared__ float As[32][132];
    __shared__ float Bs[32][64];
    const int tid = threadIdx.x;
    const int rowBase = blockIdx.x * 128;
    const int tr = tid >> 4;       // 0..15
    const int tc = tid & 15;       // 0..15
    float acc[8][4];
#pragma unroll
    for (int i = 0; i < 8; ++i)
#pragma unroll
        for (int j = 0; j < 4; ++j) acc[i][j] = 0.f;

    for (int k0 = 0; k0 < 128; k0 += 32) {
#pragma unroll
        for (int i = 0; i < 4; ++i) {
            int q = tid + i * 256;
            int m = q >> 3, k4 = (q & 7) << 2;
            int r = rowBase + m; if (r > M - 1) r = M - 1;
            float4 v = *(const float4*)(X + (size_t)r * C1 + k0 + k4);
            As[k4 + 0][m] = v.x; As[k4 + 1][m] = v.y;
            As[k4 + 2][m] = v.z; As[k4 + 3][m] = v.w;
        }
#pragma unroll
        for (int i = 0; i < 2; ++i) {
            int q = tid + i * 256;
            int kk = q >> 4, c4 = (q & 15) << 2;
            *(float4*)(&Bs[kk][c4]) = *(const float4*)(W + (size_t)(k0 + kk) * OUT_CH + c4);
        }
        __syncthreads();
#pragma unroll
        for (int k = 0; k < 32; ++k) {
            float4 a0 = *(const float4*)(&As[k][tr * 8]);
            float4 a1 = *(const float4*)(&As[k][tr * 8 + 4]);
            float4 b  = *(const float4*)(&Bs[k][tc * 4]);
            float av[8] = {a0.x, a0.y, a0.z, a0.w, a1.x, a1.y, a1.z, a1.w};
            float bv[4] = {b.x, b.y, b.z, b.w};
#pragma unroll
            for (int i = 0; i < 8; ++i)
#pragma unroll
                for (int j = 0; j < 4; ++j) acc[i][j] = fmaf(av[i], bv[j], acc[i][j]);
        }
        __syncthreads();
    }
#pragma unroll
    for (int i = 0; i < 8; ++i) {
        int r = rowBase + tr * 8 + i;
        if (r < M) {
            uint2 v;
            v.x = (unsigned int)f2bf(acc[i][0]) | ((unsigned int)f2bf(acc[i][1]) << 16);
            v.y = (unsigned int)f2bf(acc[i][2]) | ((unsigned int)f2bf(acc[i][3]) << 16);
            *(uint2*)(Hb + (size_t)r * OUT_CH + tc * 4) = v;
        }
    }
}

// ------------- layer-1 logits from bf16 h: [N,128] -> [N,8] x2 -------------
__global__ __launch_bounds__(256) void k_att1(const unsigned int* __restrict__ Hb, // as uint pairs
                                              const float* __restrict__ atts,
                                              const float* __restrict__ attd,
                                              float* __restrict__ as1,
                                              float* __restrict__ ad1, int N)
{
    int gw = (blockIdx.x * 256 + threadIdx.x) >> 6;
    int lane = threadIdx.x & 63;
    if (gw >= N) return;
    unsigned int v = Hb[(size_t)gw * 64 + lane];
    float f0 = bflo(v), f1 = bfhi(v);
    int c = 2 * lane;
    float2 avs = *(const float2*)(atts + c);
    float2 avd = *(const float2*)(attd + c);
    float s = f0 * avs.x + f1 * avs.y;
    float d = f0 * avd.x + f1 * avd.y;
#pragma unroll
    for (int k = 1; k < 8; k <<= 1) { s += __shfl_xor(s, k); d += __shfl_xor(d, k); }
    if ((lane & 7) == 0) {
        as1[gw * 8 + (lane >> 3)] = s;
        ad1[gw * 8 + (lane >> 3)] = d;
    }
}

// ------------- layer-2 logits from bf16 h: [N,64] -> [N] x2 (2 nodes/wave) -------------
__global__ __launch_bounds__(256) void k_att2(const unsigned int* __restrict__ Hb,
                                              const float* __restrict__ atts,
                                              const float* __restrict__ attd,
                                              float* __restrict__ as2,
                                              float* __restrict__ ad2, int N)
{
    int gw = (blockIdx.x * 256 + threadIdx.x) >> 6;   // wave id
    int lane = threadIdx.x & 63;
    int half = lane >> 5, c = lane & 31;
    int node = gw * 2 + half;
    if (node >= N) return;
    unsigned int v = Hb[(size_t)node * 32 + c];
    float f0 = bflo(v), f1 = bfhi(v);
    float2 avs = *(const float2*)(atts + 2 * c);
    float2 avd = *(const float2*)(attd + 2 * c);
    float s = f0 * avs.x + f1 * avs.y;
    float d = f0 * avd.x + f1 * avd.y;
#pragma unroll
    for (int k = 1; k < 32; k <<= 1) { s += __shfl_xor(s, k); d += __shfl_xor(d, k); }
    if (c == 0) { as2[node] = s; ad2[node] = d; }
}

// ---------------- CSR build ----------------
__global__ void k_hist(const int* __restrict__ ei, int* __restrict__ counts, int E, int NE)
{
    int e = blockIdx.x * blockDim.x + threadIdx.x;
    if (e >= NE) return;
    int d = (e < E) ? ei[E + e] : (e - E);
    atomicAdd(&counts[d], 1);
}

__global__ __launch_bounds__(1024) void k_bsum(const int* __restrict__ counts,
                                               int* __restrict__ bsums, int n)
{
    __shared__ int sm[1024];
    int tid = threadIdx.x;
    int i = blockIdx.x * 1024 + tid;
    sm[tid] = (i < n) ? counts[i] : 0;
    __syncthreads();
    for (int s = 512; s > 0; s >>= 1) {
        if (tid < s) sm[tid] += sm[tid + s];
        __syncthreads();
    }
    if (tid == 0) bsums[blockIdx.x] = sm[0];
}

__global__ __launch_bounds__(1024) void k_scan_bsums(int* __restrict__ bsums,
                                                     int* __restrict__ offs,
                                                     int nblk, int total, int n)
{
    __shared__ int sm[1024];
    int tid = threadIdx.x;
    int val = (tid < nblk) ? bsums[tid] : 0;
    sm[tid] = val;
    __syncthreads();
    for (int off = 1; off < 1024; off <<= 1) {
        int t = (tid >= off) ? sm[tid - off] : 0;
        __syncthreads();
        sm[tid] += t;
        __syncthreads();
    }
    if (tid < nblk) bsums[tid] = sm[tid] - val;
    if (tid == 0) offs[n] = total;
}

__global__ __launch_bounds__(1024) void k_scan_final(const int* __restrict__ counts,
                                                     const int* __restrict__ bsums,
                                                     int* __restrict__ offs, int n)
{
    __shared__ int sm[1024];
    int tid = threadIdx.x;
    int i = blockIdx.x * 1024 + tid;
    int v = (i < n) ? counts[i] : 0;
    sm[tid] = v;
    __syncthreads();
    for (int off = 1; off < 1024; off <<= 1) {
        int t = (tid >= off) ? sm[tid - off] : 0;
        __syncthreads();
        sm[tid] += t;
        __syncthreads();
    }
    if (i < n) offs[i] = bsums[blockIdx.x] + sm[tid] - v;
}

__global__ void k_scatter(const int* __restrict__ ei, const int* __restrict__ offs,
                          int* __restrict__ cursor, int* __restrict__ csr, int E, int NE)
{
    int e = blockIdx.x * blockDim.x + threadIdx.x;
    if (e >= NE) return;
    int s, d;
    if (e < E) { s = ei[e]; d = ei[E + e]; } else { s = d = e - E; }
    int pos = offs[d] + atomicAdd(&cursor[d], 1);
    csr[pos] = s;
}

// ------------- layer-1 single-pass softmax-aggregate + bias + ELU -------------
// One wave per dst node; lane owns channels (2*lane, 2*lane+1), both in head lane>>3.
__global__ __launch_bounds__(256) void k_agg1(const unsigned int* __restrict__ Hb,
                                              const float* __restrict__ as1,
                                              const float* __restrict__ ad1,
                                              const int* __restrict__ offs,
                                              const int* __restrict__ csr,
                                              const float* __restrict__ bias,
                                              float* __restrict__ Hout, int N)
{
    int i = (blockIdx.x * 256 + threadIdx.x) >> 6;
    int lane = threadIdx.x & 63;
    if (i >= N) return;
    const int h = lane >> 3;
    const int beg = offs[i], end = offs[i + 1];
    const float adv = ad1[i * 8 + h];

    float acc0 = 0.f, acc1 = 0.f, den = 0.f;
    for (int c0 = beg; c0 < end; c0 += 64) {
        int idxe = c0 + lane; if (idxe > end - 1) idxe = end - 1;
        int idx = csr[idxe];
        int cnt = end - c0; if (cnt > 64) cnt = 64;
        int t = 0;
        for (; t + 4 <= cnt; t += 4) {
            int j0 = __shfl(idx, t), j1 = __shfl(idx, t + 1);
            int j2 = __shfl(idx, t + 2), j3 = __shfl(idx, t + 3);
            float a0 = as1[j0 * 8 + h], a1 = as1[j1 * 8 + h];
            float a2 = as1[j2 * 8 + h], a3 = as1[j3 * 8 + h];
            unsigned int v0 = Hb[(size_t)j0 * 64 + lane];
            unsigned int v1 = Hb[(size_t)j1 * 64 + lane];
            unsigned int v2 = Hb[(size_t)j2 * 64 + lane];
            unsigned int v3 = Hb[(size_t)j3 * 64 + lane];
            float w0 = __expf(fminf(leaky(a0 + adv), 60.f));
            float w1 = __expf(fminf(leaky(a1 + adv), 60.f));
            float w2 = __expf(fminf(leaky(a2 + adv), 60.f));
            float w3 = __expf(fminf(leaky(a3 + adv), 60.f));
            acc0 = fmaf(w0, bflo(v0), acc0); acc1 = fmaf(w0, bfhi(v0), acc1);
            acc0 = fmaf(w1, bflo(v1), acc0); acc1 = fmaf(w1, bfhi(v1), acc1);
            acc0 = fmaf(w2, bflo(v2), acc0); acc1 = fmaf(w2, bfhi(v2), acc1);
            acc0 = fmaf(w3, bflo(v3), acc0); acc1 = fmaf(w3, bfhi(v3), acc1);
            den += (w0 + w1) + (w2 + w3);
        }
        for (; t < cnt; ++t) {
            int j = __shfl(idx, t);
            float a = as1[j * 8 + h];
            unsigned int v = Hb[(size_t)j * 64 + lane];
            float w = __expf(fminf(leaky(a + adv), 60.f));
            acc0 = fmaf(w, bflo(v), acc0); acc1 = fmaf(w, bfhi(v), acc1);
            den += w;
        }
    }
    float r = 1.f / (den + 1e-16f);
    float2 bv = *(const float2*)(bias + 2 * lane);
    float o0 = acc0 * r + bv.x;
    float o1 = acc1 * r + bv.y;
    o0 = o0 > 0.f ? o0 : expm1f(o0);
    o1 = o1 > 0.f ? o1 : expm1f(o1);
    float2 o = {o0, o1};
    *(float2*)(Hout + (size_t)i * C1 + 2 * lane) = o;
}

// ------------- layer-2 single-pass softmax-aggregate + bias + log_softmax -------------
// One wave per dst node; two edges per iteration (half-wave each); lane owns 2 channels.
__global__ __launch_bounds__(256) void k_agg2(const unsigned int* __restrict__ Hb,
                                              const float* __restrict__ as2,
                                              const float* __restrict__ ad2,
                                              const int* __restrict__ offs,
                                              const int* __restrict__ csr,
                                              const float* __restrict__ bias,
                                              float* __restrict__ out, int N)
{
    int i = (blockIdx.x * 256 + threadIdx.x) >> 6;
    int lane = threadIdx.x & 63;
    if (i >= N) return;
    const int half = lane >> 5, c = lane & 31;
    const int beg = offs[i], end = offs[i + 1];
    const float adv = ad2[i];

    float acc0 = 0.f, acc1 = 0.f, den = 0.f;
    for (int c0 = beg; c0 < end; c0 += 64) {
        int idxe = c0 + lane; if (idxe > end - 1) idxe = end - 1;
        int idx = csr[idxe];
        int cnt = end - c0; if (cnt > 64) cnt = 64;
        for (int t = 0; t < cnt; t += 2) {
            int tt = t + half;
            int tc2 = tt < cnt - 1 ? tt : cnt - 1;
            int j = __shfl(idx, tc2);
            float a = as2[j];
            unsigned int v = Hb[(size_t)j * 32 + c];
            float w = (tt < cnt) ? __expf(fminf(leaky(a + adv), 60.f)) : 0.f;
            acc0 = fmaf(w, bflo(v), acc0);
            acc1 = fmaf(w, bfhi(v), acc1);
            den += w;
        }
    }
    // combine the two halves
    acc0 += __shfl_xor(acc0, 32);
    acc1 += __shfl_xor(acc1, 32);
    den  += __shfl_xor(den, 32);

    float r = 1.f / (den + 1e-16f);
    float2 bv = *(const float2*)(bias + 2 * c);
    float o0 = acc0 * r + bv.x;
    float o1 = acc1 * r + bv.y;
    // log_softmax over 64 channels = 32 lanes x 2 (within each half; halves identical)
    float mx = fmaxf(o0, o1);
#pragma unroll
    for (int k = 1; k < 32; k <<= 1) mx = fmaxf(mx, __shfl_xor(mx, k));
    float s = __expf(o0 - mx) + __expf(o1 - mx);
#pragma unroll
    for (int k = 1; k < 32; k <<= 1) s += __shfl_xor(s, k);
    float ls = __logf(s);
    if (half == 0) {
        float2 o = {(o0 - mx) - ls, (o1 - mx) - ls};
        *(float2*)(out + (size_t)i * OUT_CH + 2 * c) = o;
    }
}

extern "C" void kernel_launch(void* const* d_in, const int* in_sizes, int n_in,
                              void* d_out, int out_size, void* d_ws, size_t ws_size,
                              hipStream_t stream)
{
    const float* x    = (const float*)d_in[0];
    const int*   ei   = (const int*)  d_in[1];
    const float* W1   = (const float*)d_in[2];
    const float* atS1 = (const float*)d_in[3];
    const float* atD1 = (const float*)d_in[4];
    const float* b1   = (const float*)d_in[5];
    const float* W2   = (const float*)d_in[6];
    const float* atS2 = (const float*)d_in[7];
    const float* atD2 = (const float*)d_in[8];
    const float* b2   = (const float*)d_in[9];
    float* out = (float*)d_out;

    const int N  = in_sizes[0] / IN_C;
    const int E  = in_sizes[1] / 2;
    const int NE = E + N;

    // ---- workspace layout ----
    char* p = (char*)d_ws;
    unsigned short* h1b = (unsigned short*)p; p += (size_t)N * C1 * 2;      // bf16 [N,128]
    float* hout = (float*)p;                  p += (size_t)N * C1 * 4;      // f32  [N,128]
    unsigned short* h2b = (unsigned short*)p; p += (size_t)N * OUT_CH * 2;  // bf16 [N,64]
    float* as1  = (float*)p;                  p += (size_t)N * 8 * 4;
    float* ad1  = (float*)p;                  p += (size_t)N * 8 * 4;
    float* as2  = (float*)p;                  p += (size_t)N * 4;
    float* ad2  = (float*)p;                  p += (size_t)N * 4;
    int* counts = (int*)p;                    p += (size_t)N * 4;
    int* offs   = (int*)p;                    p += (size_t)(N + 1) * 4;
    int* cursor = (int*)p;                    p += (size_t)N * 4;
    int* bsums  = (int*)p;                    p += 1024 * 4;
    int* csr    = (int*)p;                    p += (size_t)NE * 4;

    const int nblk = (N + 1023) / 1024;

    hipMemsetAsync(counts, 0, sizeof(int) * (size_t)(3 * N + 1), stream);

    // layer 1 GEMM + logits
    k_gemm1<<<(N + 63) / 64, 256, 0, stream>>>(x, W1, h1b, N);
    k_att1<<<(N + 3) / 4, 256, 0, stream>>>((const unsigned int*)h1b, atS1, atD1, as1, ad1, N);

    // CSR build
    k_hist<<<(NE + 255) / 256, 256, 0, stream>>>(ei, counts, E, NE);
    k_bsum<<<nblk, 1024, 0, stream>>>(counts, bsums, N);
    k_scan_bsums<<<1, 1024, 0, stream>>>(bsums, offs, nblk, NE, N);
    k_scan_final<<<nblk, 1024, 0, stream>>>(counts, bsums, offs, N);
    k_scatter<<<(NE + 255) / 256, 256, 0, stream>>>(ei, offs, cursor, csr, E, NE);

    // layer 1 aggregate (+bias+ELU)
    k_agg1<<<(N + 3) / 4, 256, 0, stream>>>((const unsigned int*)h1b, as1, ad1, offs, csr, b1, hout, N);

    // layer 2
    k_gemm2<<<(N + 127) / 128, 256, 0, stream>>>(hout, W2, h2b, N);
    k_att2<<<(N + 7) / 8, 256, 0, stream>>>((const unsigned int*)h2b, atS2, atD2, as2, ad2, N);
    k_agg2<<<(N + 3) / 4, 256, 0, stream>>>((const unsigned int*)h2b, as2, ad2, offs, csr, b2, out, N);
}

// Round 3
// 412.229 us; speedup vs baseline: 2.2551x; 1.2270x over previous
//
#include <hip/hip_runtime.h>
#include <hip/hip_bf16.h>

#define IN_C 256
#define C1   128   // HEADS*HID
#define OUT_CH 64
#define NEG 0.2f

__device__ __forceinline__ float leaky(float x) { return x > 0.f ? x : NEG * x; }
__device__ __forceinline__ unsigned short f2bf(float f) {
    unsigned int x = __float_as_uint(f);
    unsigned int r = (x + 0x7fffu + ((x >> 16) & 1u)) >> 16;   // RNE
    return (unsigned short)r;
}
__device__ __forceinline__ float bflo(unsigned int v) { return __uint_as_float(v << 16); }
__device__ __forceinline__ float bfhi(unsigned int v) { return __uint_as_float(v & 0xffff0000u); }

// ---- GEMM1: [M,256] x [256,128] -> bf16 [M,128], fused att1 logits ----
__global__ __launch_bounds__(256) void k_gemm1(const float* __restrict__ X,
                                               const float* __restrict__ W,
                                               const float* __restrict__ atts,
                                               const float* __restrict__ attd,
                                               unsigned short* __restrict__ Hb,
                                               float* __restrict__ as1,
                                               float* __restrict__ ad1, int M)
{
    __shared__ float As[32][68];   // transposed [k][m]
    __shared__ float Bs[32][128];
    const int tid = threadIdx.x;
    const int rowBase = blockIdx.x * 64;
    const int tr = tid >> 5;       // 0..7
    const int tc = tid & 31;       // 0..31
    float acc[8][4];
#pragma unroll
    for (int i = 0; i < 8; ++i)
#pragma unroll
        for (int j = 0; j < 4; ++j) acc[i][j] = 0.f;

    for (int k0 = 0; k0 < 256; k0 += 32) {
#pragma unroll
        for (int i = 0; i < 2; ++i) {
            int q = tid + i * 256;
            int m = q >> 3, k4 = (q & 7) << 2;
            int r = rowBase + m; if (r > M - 1) r = M - 1;
            float4 v = *(const float4*)(X + (size_t)r * IN_C + k0 + k4);
            As[k4 + 0][m] = v.x; As[k4 + 1][m] = v.y;
            As[k4 + 2][m] = v.z; As[k4 + 3][m] = v.w;
        }
#pragma unroll
        for (int i = 0; i < 4; ++i) {
            int q = tid + i * 256;
            int kk = q >> 5, c4 = (q & 31) << 2;
            *(float4*)(&Bs[kk][c4]) = *(const float4*)(W + (size_t)(k0 + kk) * C1 + c4);
        }
        __syncthreads();
#pragma unroll
        for (int k = 0; k < 32; ++k) {
            float4 a0 = *(const float4*)(&As[k][tr * 8]);
            float4 a1 = *(const float4*)(&As[k][tr * 8 + 4]);
            float4 b  = *(const float4*)(&Bs[k][tc * 4]);
            float av[8] = {a0.x, a0.y, a0.z, a0.w, a1.x, a1.y, a1.z, a1.w};
            float bv[4] = {b.x, b.y, b.z, b.w};
#pragma unroll
            for (int i = 0; i < 8; ++i)
#pragma unroll
                for (int j = 0; j < 4; ++j) acc[i][j] = fmaf(av[i], bv[j], acc[i][j]);
        }
        __syncthreads();
    }
    const int h = tc >> 2;                         // head of this lane's 4 cols
    const float4 avs = *(const float4*)(atts + tc * 4);
    const float4 avd = *(const float4*)(attd + tc * 4);
#pragma unroll
    for (int i = 0; i < 8; ++i) {
        int r = rowBase + tr * 8 + i;
        // attention partial dots + 4-lane reduce (lanes tc = 4h..4h+3 are consecutive)
        float s = acc[i][0] * avs.x + acc[i][1] * avs.y + acc[i][2] * avs.z + acc[i][3] * avs.w;
        float d = acc[i][0] * avd.x + acc[i][1] * avd.y + acc[i][2] * avd.z + acc[i][3] * avd.w;
        s += __shfl_xor(s, 1); s += __shfl_xor(s, 2);
        d += __shfl_xor(d, 1); d += __shfl_xor(d, 2);
        if (r < M) {
            uint2 v;
            v.x = (unsigned int)f2bf(acc[i][0]) | ((unsigned int)f2bf(acc[i][1]) << 16);
            v.y = (unsigned int)f2bf(acc[i][2]) | ((unsigned int)f2bf(acc[i][3]) << 16);
            *(uint2*)(Hb + (size_t)r * C1 + tc * 4) = v;
            if ((tc & 3) == 0) { as1[r * 8 + h] = s; ad1[r * 8 + h] = d; }
        }
    }
}

// ---- GEMM2: [M,128] x [128,64] -> bf16 [M,64], fused att2 logits ----
__global__ __launch_bounds__(256) void k_gemm2(const float* __restrict__ X,
                                               const float* __restrict__ W,
                                               const float* __restrict__ atts,
                                               const float* __restrict__ attd,
                                               unsigned short* __restrict__ Hb,
                                               float* __restrict__ as2,
                                               float* __restrict__ ad2, int M)
{
    __shared__ float As[32][132];
    __shared__ float Bs[32][64];
    const int tid = threadIdx.x;
    const int rowBase = blockIdx.x * 128;
    const int tr = tid >> 4;       // 0..15
    const int tc = tid & 15;       // 0..15
    float acc[8][4];
#pragma unroll
    for (int i = 0; i < 8; ++i)
#pragma unroll
        for (int j = 0; j < 4; ++j) acc[i][j] = 0.f;

    for (int k0 = 0; k0 < 128; k0 += 32) {
#pragma unroll
        for (int i = 0; i < 4; ++i) {
            int q = tid + i * 256;
            int m = q >> 3, k4 = (q & 7) << 2;
            int r = rowBase + m; if (r > M - 1) r = M - 1;
            float4 v = *(const float4*)(X + (size_t)r * C1 + k0 + k4);
            As[k4 + 0][m] = v.x; As[k4 + 1][m] = v.y;
            As[k4 + 2][m] = v.z; As[k4 + 3][m] = v.w;
        }
#pragma unroll
        for (int i = 0; i < 2; ++i) {
            int q = tid + i * 256;
            int kk = q >> 4, c4 = (q & 15) << 2;
            *(float4*)(&Bs[kk][c4]) = *(const float4*)(W + (size_t)(k0 + kk) * OUT_CH + c4);
        }
        __syncthreads();
#pragma unroll
        for (int k = 0; k < 32; ++k) {
            float4 a0 = *(const float4*)(&As[k][tr * 8]);
            float4 a1 = *(const float4*)(&As[k][tr * 8 + 4]);
            float4 b  = *(const float4*)(&Bs[k][tc * 4]);
            float av[8] = {a0.x, a0.y, a0.z, a0.w, a1.x, a1.y, a1.z, a1.w};
            float bv[4] = {b.x, b.y, b.z, b.w};
#pragma unroll
            for (int i = 0; i < 8; ++i)
#pragma unroll
                for (int j = 0; j < 4; ++j) acc[i][j] = fmaf(av[i], bv[j], acc[i][j]);
        }
        __syncthreads();
    }
    const float4 avs = *(const float4*)(atts + tc * 4);
    const float4 avd = *(const float4*)(attd + tc * 4);
#pragma unroll
    for (int i = 0; i < 8; ++i) {
        int r = rowBase + tr * 8 + i;
        float s = acc[i][0] * avs.x + acc[i][1] * avs.y + acc[i][2] * avs.z + acc[i][3] * avs.w;
        float d = acc[i][0] * avd.x + acc[i][1] * avd.y + acc[i][2] * avd.z + acc[i][3] * avd.w;
#pragma unroll
        for (int k = 1; k < 16; k <<= 1) { s += __shfl_xor(s, k); d += __shfl_xor(d, k); }
        if (r < M) {
            uint2 v;
            v.x = (unsigned int)f2bf(acc[i][0]) | ((unsigned int)f2bf(acc[i][1]) << 16);
            v.y = (unsigned int)f2bf(acc[i][2]) | ((unsigned int)f2bf(acc[i][3]) << 16);
            *(uint2*)(Hb + (size_t)r * OUT_CH + tc * 4) = v;
            if (tc == 0) { as2[r] = s; ad2[r] = d; }
        }
    }
}

// ---------------- CSR build ----------------
// histogram + per-edge rank in one atomic
__global__ void k_hist(const int* __restrict__ ei, int* __restrict__ counts,
                       int* __restrict__ rank, int E, int NE)
{
    int e = blockIdx.x * blockDim.x + threadIdx.x;
    if (e >= NE) return;
    int d = (e < E) ? ei[E + e] : (e - E);
    rank[e] = atomicAdd(&counts[d], 1);
}

__global__ __launch_bounds__(1024) void k_bsum(const int* __restrict__ counts,
                                               int* __restrict__ bsums, int n)
{
    __shared__ int sm[1024];
    int tid = threadIdx.x;
    int i = blockIdx.x * 1024 + tid;
    sm[tid] = (i < n) ? counts[i] : 0;
    __syncthreads();
    for (int s = 512; s > 0; s >>= 1) {
        if (tid < s) sm[tid] += sm[tid + s];
        __syncthreads();
    }
    if (tid == 0) bsums[blockIdx.x] = sm[0];
}

__global__ __launch_bounds__(1024) void k_scan_bsums(int* __restrict__ bsums,
                                                     int* __restrict__ offs,
                                                     int nblk, int total, int n)
{
    __shared__ int sm[1024];
    int tid = threadIdx.x;
    int val = (tid < nblk) ? bsums[tid] : 0;
    sm[tid] = val;
    __syncthreads();
    for (int off = 1; off < 1024; off <<= 1) {
        int t = (tid >= off) ? sm[tid - off] : 0;
        __syncthreads();
        sm[tid] += t;
        __syncthreads();
    }
    if (tid < nblk) bsums[tid] = sm[tid] - val;
    if (tid == 0) offs[n] = total;
}

__global__ __launch_bounds__(1024) void k_scan_final(const int* __restrict__ counts,
                                                     const int* __restrict__ bsums,
                                                     int* __restrict__ offs, int n)
{
    __shared__ int sm[1024];
    int tid = threadIdx.x;
    int i = blockIdx.x * 1024 + tid;
    int v = (i < n) ? counts[i] : 0;
    sm[tid] = v;
    __syncthreads();
    for (int off = 1; off < 1024; off <<= 1) {
        int t = (tid >= off) ? sm[tid - off] : 0;
        __syncthreads();
        sm[tid] += t;
        __syncthreads();
    }
    if (i < n) offs[i] = bsums[blockIdx.x] + sm[tid] - v;
}

// atomic-free scatter using precomputed ranks
__global__ void k_scatter(const int* __restrict__ ei, const int* __restrict__ offs,
                          const int* __restrict__ rank, int* __restrict__ csr, int E, int NE)
{
    int e = blockIdx.x * blockDim.x + threadIdx.x;
    if (e >= NE) return;
    int s, d;
    if (e < E) { s = ei[e]; d = ei[E + e]; } else { s = d = e - E; }
    csr[offs[d] + rank[e]] = s;
}

// ------------- layer-1 single-pass softmax-aggregate + bias + ELU -------------
__global__ __launch_bounds__(256) void k_agg1(const unsigned int* __restrict__ Hb,
                                              const float* __restrict__ as1,
                                              const float* __restrict__ ad1,
                                              const int* __restrict__ offs,
                                              const int* __restrict__ csr,
                                              const float* __restrict__ bias,
                                              float* __restrict__ Hout, int N)
{
    int i = (blockIdx.x * 256 + threadIdx.x) >> 6;
    int lane = threadIdx.x & 63;
    if (i >= N) return;
    const int h = lane >> 3;
    const int beg = offs[i], end = offs[i + 1];
    const float adv = ad1[i * 8 + h];

    float acc0 = 0.f, acc1 = 0.f, den = 0.f;
    for (int c0 = beg; c0 < end; c0 += 64) {
        int idxe = c0 + lane; if (idxe > end - 1) idxe = end - 1;
        int idx = csr[idxe];
        int cnt = end - c0; if (cnt > 64) cnt = 64;
        int t = 0;
        for (; t + 4 <= cnt; t += 4) {
            int j0 = __shfl(idx, t), j1 = __shfl(idx, t + 1);
            int j2 = __shfl(idx, t + 2), j3 = __shfl(idx, t + 3);
            float a0 = as1[j0 * 8 + h], a1 = as1[j1 * 8 + h];
            float a2 = as1[j2 * 8 + h], a3 = as1[j3 * 8 + h];
            unsigned int v0 = Hb[(size_t)j0 * 64 + lane];
            unsigned int v1 = Hb[(size_t)j1 * 64 + lane];
            unsigned int v2 = Hb[(size_t)j2 * 64 + lane];
            unsigned int v3 = Hb[(size_t)j3 * 64 + lane];
            float w0 = __expf(fminf(leaky(a0 + adv), 60.f));
            float w1 = __expf(fminf(leaky(a1 + adv), 60.f));
            float w2 = __expf(fminf(leaky(a2 + adv), 60.f));
            float w3 = __expf(fminf(leaky(a3 + adv), 60.f));
            acc0 = fmaf(w0, bflo(v0), acc0); acc1 = fmaf(w0, bfhi(v0), acc1);
            acc0 = fmaf(w1, bflo(v1), acc0); acc1 = fmaf(w1, bfhi(v1), acc1);
            acc0 = fmaf(w2, bflo(v2), acc0); acc1 = fmaf(w2, bfhi(v2), acc1);
            acc0 = fmaf(w3, bflo(v3), acc0); acc1 = fmaf(w3, bfhi(v3), acc1);
            den += (w0 + w1) + (w2 + w3);
        }
        for (; t < cnt; ++t) {
            int j = __shfl(idx, t);
            float a = as1[j * 8 + h];
            unsigned int v = Hb[(size_t)j * 64 + lane];
            float w = __expf(fminf(leaky(a + adv), 60.f));
            acc0 = fmaf(w, bflo(v), acc0); acc1 = fmaf(w, bfhi(v), acc1);
            den += w;
        }
    }
    float r = 1.f / (den + 1e-16f);
    float2 bv = *(const float2*)(bias + 2 * lane);
    float o0 = acc0 * r + bv.x;
    float o1 = acc1 * r + bv.y;
    o0 = o0 > 0.f ? o0 : expm1f(o0);
    o1 = o1 > 0.f ? o1 : expm1f(o1);
    float2 o = {o0, o1};
    *(float2*)(Hout + (size_t)i * C1 + 2 * lane) = o;
}

// ------------- layer-2 single-pass softmax-aggregate + bias + log_softmax -------------
__global__ __launch_bounds__(256) void k_agg2(const unsigned int* __restrict__ Hb,
                                              const float* __restrict__ as2,
                                              const float* __restrict__ ad2,
                                              const int* __restrict__ offs,
                                              const int* __restrict__ csr,
                                              const float* __restrict__ bias,
                                              float* __restrict__ out, int N)
{
    int i = (blockIdx.x * 256 + threadIdx.x) >> 6;
    int lane = threadIdx.x & 63;
    if (i >= N) return;
    const int half = lane >> 5, c = lane & 31;
    const int beg = offs[i], end = offs[i + 1];
    const float adv = ad2[i];

    float acc0 = 0.f, acc1 = 0.f, den = 0.f;
    for (int c0 = beg; c0 < end; c0 += 64) {
        int idxe = c0 + lane; if (idxe > end - 1) idxe = end - 1;
        int idx = csr[idxe];
        int cnt = end - c0; if (cnt > 64) cnt = 64;
        for (int t = 0; t < cnt; t += 2) {
            int tt = t + half;
            int tc2 = tt < cnt - 1 ? tt : cnt - 1;
            int j = __shfl(idx, tc2);
            float a = as2[j];
            unsigned int v = Hb[(size_t)j * 32 + c];
            float w = (tt < cnt) ? __expf(fminf(leaky(a + adv), 60.f)) : 0.f;
            acc0 = fmaf(w, bflo(v), acc0);
            acc1 = fmaf(w, bfhi(v), acc1);
            den += w;
        }
    }
    acc0 += __shfl_xor(acc0, 32);
    acc1 += __shfl_xor(acc1, 32);
    den  += __shfl_xor(den, 32);

    float r = 1.f / (den + 1e-16f);
    float2 bv = *(const float2*)(bias + 2 * c);
    float o0 = acc0 * r + bv.x;
    float o1 = acc1 * r + bv.y;
    float mx = fmaxf(o0, o1);
#pragma unroll
    for (int k = 1; k < 32; k <<= 1) mx = fmaxf(mx, __shfl_xor(mx, k));
    float s = __expf(o0 - mx) + __expf(o1 - mx);
#pragma unroll
    for (int k = 1; k < 32; k <<= 1) s += __shfl_xor(s, k);
    float ls = __logf(s);
    if (half == 0) {
        float2 o = {(o0 - mx) - ls, (o1 - mx) - ls};
        *(float2*)(out + (size_t)i * OUT_CH + 2 * c) = o;
    }
}

extern "C" void kernel_launch(void* const* d_in, const int* in_sizes, int n_in,
                              void* d_out, int out_size, void* d_ws, size_t ws_size,
                              hipStream_t stream)
{
    const float* x    = (const float*)d_in[0];
    const int*   ei   = (const int*)  d_in[1];
    const float* W1   = (const float*)d_in[2];
    const float* atS1 = (const float*)d_in[3];
    const float* atD1 = (const float*)d_in[4];
    const float* b1   = (const float*)d_in[5];
    const float* W2   = (const float*)d_in[6];
    const float* atS2 = (const float*)d_in[7];
    const float* atD2 = (const float*)d_in[8];
    const float* b2   = (const float*)d_in[9];
    float* out = (float*)d_out;

    const int N  = in_sizes[0] / IN_C;
    const int E  = in_sizes[1] / 2;
    const int NE = E + N;

    // ---- workspace layout ----
    char* p = (char*)d_ws;
    unsigned short* h1b = (unsigned short*)p; p += (size_t)N * C1 * 2;      // bf16 [N,128]
    float* hout = (float*)p;                  p += (size_t)N * C1 * 4;      // f32  [N,128]
    unsigned short* h2b = (unsigned short*)p; p += (size_t)N * OUT_CH * 2;  // bf16 [N,64]
    float* as1  = (float*)p;                  p += (size_t)N * 8 * 4;
    float* ad1  = (float*)p;                  p += (size_t)N * 8 * 4;
    float* as2  = (float*)p;                  p += (size_t)N * 4;
    float* ad2  = (float*)p;                  p += (size_t)N * 4;
    int* counts = (int*)p;                    p += (size_t)N * 4;
    int* offs   = (int*)p;                    p += (size_t)(N + 1) * 4;
    int* bsums  = (int*)p;                    p += 1024 * 4;
    int* rank   = (int*)p;                    p += (size_t)NE * 4;
    int* csr    = (int*)p;                    p += (size_t)NE * 4;

    const int nblk = (N + 1023) / 1024;

    hipMemsetAsync(counts, 0, sizeof(int) * (size_t)N, stream);

    // layer 1 GEMM + fused logits
    k_gemm1<<<(N + 63) / 64, 256, 0, stream>>>(x, W1, atS1, atD1, h1b, as1, ad1, N);

    // CSR build
    k_hist<<<(NE + 255) / 256, 256, 0, stream>>>(ei, counts, rank, E, NE);
    k_bsum<<<nblk, 1024, 0, stream>>>(counts, bsums, N);
    k_scan_bsums<<<1, 1024, 0, stream>>>(bsums, offs, nblk, NE, N);
    k_scan_final<<<nblk, 1024, 0, stream>>>(counts, bsums, offs, N);
    k_scatter<<<(NE + 255) / 256, 256, 0, stream>>>(ei, offs, rank, csr, E, NE);

    // layer 1 aggregate (+bias+ELU)
    k_agg1<<<(N + 3) / 4, 256, 0, stream>>>((const unsigned int*)h1b, as1, ad1, offs, csr, b1, hout, N);

    // layer 2 GEMM + fused logits, then aggregate
    k_gemm2<<<(N + 127) / 128, 256, 0, stream>>>(hout, W2, atS2, atD2, h2b, as2, ad2, N);
    k_agg2<<<(N + 3) / 4, 256, 0, stream>>>((const unsigned int*)h2b, as2, ad2, offs, csr, b2, out, N);
}

// Round 4
// 327.671 us; speedup vs baseline: 2.8370x; 1.2581x over previous
//
#include <hip/hip_runtime.h>
#include <hip/hip_bf16.h>

#define IN_C 256
#define C1   128   // HEADS*HID
#define OUT_CH 64
#define NEG 0.2f
#define STR 40     // LDS row stride in shorts (80B): 16B-aligned, conflict-free b128

typedef __attribute__((ext_vector_type(8))) short bf16x8;
typedef __attribute__((ext_vector_type(4))) float f32x4;

__device__ __forceinline__ float leaky(float x) { return x > 0.f ? x : NEG * x; }
__device__ __forceinline__ unsigned short f2bf(float f) {
    unsigned int x = __float_as_uint(f);
    unsigned int r = (x + 0x7fffu + ((x >> 16) & 1u)) >> 16;   // RNE
    return (unsigned short)r;
}
__device__ __forceinline__ float bflo(unsigned int v) { return __uint_as_float(v << 16); }
__device__ __forceinline__ float bfhi(unsigned int v) { return __uint_as_float(v & 0xffff0000u); }

// ---- one-time weight transpose+cast: Wt1[n][k] bf16, Wt2[n][k] bf16 ----
__global__ __launch_bounds__(256) void k_prep(const float* __restrict__ W1,
                                              const float* __restrict__ W2,
                                              unsigned short* __restrict__ Wt1,
                                              unsigned short* __restrict__ Wt2)
{
    int t = blockIdx.x * 256 + threadIdx.x;
    if (t < 256 * 128) {
        int k = t >> 7, n = t & 127;
        Wt1[n * 256 + k] = f2bf(W1[t]);
    } else {
        int q = t - 256 * 128;
        if (q < 128 * 64) {
            int k = q >> 6, n = q & 63;
            Wt2[n * 128 + k] = f2bf(W2[q]);
        }
    }
}

// ---- GEMM1 (MFMA bf16): [M,256]f32 x Wt1 -> bf16 [M,128] + fused att1 logits ----
__global__ __launch_bounds__(256) void k_gemm1(const float* __restrict__ X,
                                               const unsigned short* __restrict__ Wt1,
                                               const float* __restrict__ atts,
                                               const float* __restrict__ attd,
                                               unsigned short* __restrict__ Hb,
                                               float* __restrict__ as1,
                                               float* __restrict__ ad1, int M)
{
    __shared__ unsigned short As[64 * STR];
    __shared__ unsigned short Bs[128 * STR];
    const int tid = threadIdx.x;
    const int w = tid >> 6, lane = tid & 63;
    const int l15 = lane & 15, kg = lane >> 4;
    const int rowBase = blockIdx.x * 64;

    f32x4 acc[8];
#pragma unroll
    for (int i = 0; i < 8; ++i) acc[i] = (f32x4){0.f, 0.f, 0.f, 0.f};

    for (int k0 = 0; k0 < 256; k0 += 32) {
        // stage A: 64 rows x 32 k, f32 -> bf16
        {
            int row = tid >> 2, ko = (tid & 3) * 8;
            int r = rowBase + row; if (r > M - 1) r = M - 1;
            const float* src = X + (size_t)r * IN_C + k0 + ko;
            float4 f0 = *(const float4*)src;
            float4 f1 = *(const float4*)(src + 4);
            uint4 pk;
            pk.x = (unsigned int)f2bf(f0.x) | ((unsigned int)f2bf(f0.y) << 16);
            pk.y = (unsigned int)f2bf(f0.z) | ((unsigned int)f2bf(f0.w) << 16);
            pk.z = (unsigned int)f2bf(f1.x) | ((unsigned int)f2bf(f1.y) << 16);
            pk.w = (unsigned int)f2bf(f1.z) | ((unsigned int)f2bf(f1.w) << 16);
            *(uint4*)(&As[row * STR + ko]) = pk;
        }
        // stage B: 128 n-rows x 32 k, bf16 copy
        {
            int n = tid >> 1, ko = (tid & 1) * 16;
            const unsigned short* src = Wt1 + n * 256 + k0 + ko;
            uint4 b0 = *(const uint4*)src;
            uint4 b1 = *(const uint4*)(src + 8);
            *(uint4*)(&Bs[n * STR + ko]) = b0;
            *(uint4*)(&Bs[n * STR + ko + 8]) = b1;
        }
        __syncthreads();
        bf16x8 a = *(const bf16x8*)(&As[(w * 16 + l15) * STR + kg * 8]);
#pragma unroll
        for (int i = 0; i < 8; ++i) {
            bf16x8 b = *(const bf16x8*)(&Bs[(i * 16 + l15) * STR + kg * 8]);
            acc[i] = __builtin_amdgcn_mfma_f32_16x16x32_bf16(a, b, acc[i], 0, 0, 0);
        }
        __syncthreads();
    }

    // epilogue: store h (bf16) + fused att logits (head i == n-tile i)
    float avs[8], avd[8];
#pragma unroll
    for (int i = 0; i < 8; ++i) {
        avs[i] = atts[i * 16 + l15];
        avd[i] = attd[i * 16 + l15];
    }
#pragma unroll
    for (int r = 0; r < 4; ++r) {
        int row = rowBase + w * 16 + 4 * kg + r;
        bool ok = row < M;
#pragma unroll
        for (int i = 0; i < 8; ++i) {
            float v = acc[i][r];
            if (ok) Hb[(size_t)row * C1 + i * 16 + l15] = f2bf(v);
            float s = v * avs[i];
            float d = v * avd[i];
            s += __shfl_xor(s, 1); s += __shfl_xor(s, 2);
            s += __shfl_xor(s, 4); s += __shfl_xor(s, 8);
            d += __shfl_xor(d, 1); d += __shfl_xor(d, 2);
            d += __shfl_xor(d, 4); d += __shfl_xor(d, 8);
            if (ok && l15 == 0) { as1[row * 8 + i] = s; ad1[row * 8 + i] = d; }
        }
    }
}

// ---- GEMM2 (MFMA bf16): [M,128]bf16 x Wt2 -> bf16 [M,64] + fused att2 logits ----
__global__ __launch_bounds__(256) void k_gemm2(const unsigned short* __restrict__ Xb,
                                               const unsigned short* __restrict__ Wt2,
                                               const float* __restrict__ atts,
                                               const float* __restrict__ attd,
                                               unsigned short* __restrict__ Hb,
                                               float* __restrict__ as2,
                                               float* __restrict__ ad2, int M)
{
    __shared__ unsigned short As[64 * STR];
    __shared__ unsigned short Bs[64 * STR];
    const int tid = threadIdx.x;
    const int w = tid >> 6, lane = tid & 63;
    const int l15 = lane & 15, kg = lane >> 4;
    const int rowBase = blockIdx.x * 64;

    f32x4 acc[4];
#pragma unroll
    for (int i = 0; i < 4; ++i) acc[i] = (f32x4){0.f, 0.f, 0.f, 0.f};

    for (int k0 = 0; k0 < 128; k0 += 32) {
        {
            int row = tid >> 2, ko = (tid & 3) * 8;
            int r = rowBase + row; if (r > M - 1) r = M - 1;
            uint4 v = *(const uint4*)(Xb + (size_t)r * C1 + k0 + ko);
            *(uint4*)(&As[row * STR + ko]) = v;
        }
        {
            int n = tid >> 2, ko = (tid & 3) * 8;
            uint4 v = *(const uint4*)(Wt2 + n * 128 + k0 + ko);
            *(uint4*)(&Bs[n * STR + ko]) = v;
        }
        __syncthreads();
        bf16x8 a = *(const bf16x8*)(&As[(w * 16 + l15) * STR + kg * 8]);
#pragma unroll
        for (int i = 0; i < 4; ++i) {
            bf16x8 b = *(const bf16x8*)(&Bs[(i * 16 + l15) * STR + kg * 8]);
            acc[i] = __builtin_amdgcn_mfma_f32_16x16x32_bf16(a, b, acc[i], 0, 0, 0);
        }
        __syncthreads();
    }

    float avs[4], avd[4];
#pragma unroll
    for (int i = 0; i < 4; ++i) {
        avs[i] = atts[i * 16 + l15];
        avd[i] = attd[i * 16 + l15];
    }
#pragma unroll
    for (int r = 0; r < 4; ++r) {
        int row = rowBase + w * 16 + 4 * kg + r;
        bool ok = row < M;
        float s = 0.f, d = 0.f;
#pragma unroll
        for (int i = 0; i < 4; ++i) {
            float v = acc[i][r];
            if (ok) Hb[(size_t)row * OUT_CH + i * 16 + l15] = f2bf(v);
            s = fmaf(v, avs[i], s);
            d = fmaf(v, avd[i], d);
        }
        s += __shfl_xor(s, 1); s += __shfl_xor(s, 2);
        s += __shfl_xor(s, 4); s += __shfl_xor(s, 8);
        d += __shfl_xor(d, 1); d += __shfl_xor(d, 2);
        d += __shfl_xor(d, 4); d += __shfl_xor(d, 8);
        if (ok && l15 == 0) { as2[row] = s; ad2[row] = d; }
    }
}

// ---------------- CSR build ----------------
__global__ void k_hist(const int* __restrict__ ei, int* __restrict__ counts,
                       int* __restrict__ rank, int E, int NE)
{
    int e = blockIdx.x * blockDim.x + threadIdx.x;
    if (e >= NE) return;
    int d = (e < E) ? ei[E + e] : (e - E);
    rank[e] = atomicAdd(&counts[d], 1);
}

__global__ __launch_bounds__(1024) void k_bsum(const int* __restrict__ counts,
                                               int* __restrict__ bsums, int n)
{
    __shared__ int sm[1024];
    int tid = threadIdx.x;
    int i = blockIdx.x * 1024 + tid;
    sm[tid] = (i < n) ? counts[i] : 0;
    __syncthreads();
    for (int s = 512; s > 0; s >>= 1) {
        if (tid < s) sm[tid] += sm[tid + s];
        __syncthreads();
    }
    if (tid == 0) bsums[blockIdx.x] = sm[0];
}

__global__ __launch_bounds__(1024) void k_scan_bsums(int* __restrict__ bsums,
                                                     int* __restrict__ offs,
                                                     int nblk, int total, int n)
{
    __shared__ int sm[1024];
    int tid = threadIdx.x;
    int val = (tid < nblk) ? bsums[tid] : 0;
    sm[tid] = val;
    __syncthreads();
    for (int off = 1; off < 1024; off <<= 1) {
        int t = (tid >= off) ? sm[tid - off] : 0;
        __syncthreads();
        sm[tid] += t;
        __syncthreads();
    }
    if (tid < nblk) bsums[tid] = sm[tid] - val;
    if (tid == 0) offs[n] = total;
}

__global__ __launch_bounds__(1024) void k_scan_final(const int* __restrict__ counts,
                                                     const int* __restrict__ bsums,
                                                     int* __restrict__ offs, int n)
{
    __shared__ int sm[1024];
    int tid = threadIdx.x;
    int i = blockIdx.x * 1024 + tid;
    int v = (i < n) ? counts[i] : 0;
    sm[tid] = v;
    __syncthreads();
    for (int off = 1; off < 1024; off <<= 1) {
        int t = (tid >= off) ? sm[tid - off] : 0;
        __syncthreads();
        sm[tid] += t;
        __syncthreads();
    }
    if (i < n) offs[i] = bsums[blockIdx.x] + sm[tid] - v;
}

__global__ void k_scatter(const int* __restrict__ ei, const int* __restrict__ offs,
                          const int* __restrict__ rank, int* __restrict__ csr, int E, int NE)
{
    int e = blockIdx.x * blockDim.x + threadIdx.x;
    if (e >= NE) return;
    int s, d;
    if (e < E) { s = ei[e]; d = ei[E + e]; } else { s = d = e - E; }
    csr[offs[d] + rank[e]] = s;
}

// ------------- layer-1 single-pass softmax-aggregate + bias + ELU -> bf16 -------------
__global__ __launch_bounds__(256) void k_agg1(const unsigned int* __restrict__ Hb,
                                              const float* __restrict__ as1,
                                              const float* __restrict__ ad1,
                                              const int* __restrict__ offs,
                                              const int* __restrict__ csr,
                                              const float* __restrict__ bias,
                                              unsigned int* __restrict__ Hout, int N)
{
    int i = (blockIdx.x * 256 + threadIdx.x) >> 6;
    int lane = threadIdx.x & 63;
    if (i >= N) return;
    const int h = lane >> 3;
    const int beg = offs[i], end = offs[i + 1];
    const float adv = ad1[i * 8 + h];

    float acc0 = 0.f, acc1 = 0.f, den = 0.f;
    for (int c0 = beg; c0 < end; c0 += 64) {
        int idxe = c0 + lane; if (idxe > end - 1) idxe = end - 1;
        int idx = csr[idxe];
        int cnt = end - c0; if (cnt > 64) cnt = 64;
        int t = 0;
        for (; t + 4 <= cnt; t += 4) {
            int j0 = __shfl(idx, t), j1 = __shfl(idx, t + 1);
            int j2 = __shfl(idx, t + 2), j3 = __shfl(idx, t + 3);
            float a0 = as1[j0 * 8 + h], a1 = as1[j1 * 8 + h];
            float a2 = as1[j2 * 8 + h], a3 = as1[j3 * 8 + h];
            unsigned int v0 = Hb[(size_t)j0 * 64 + lane];
            unsigned int v1 = Hb[(size_t)j1 * 64 + lane];
            unsigned int v2 = Hb[(size_t)j2 * 64 + lane];
            unsigned int v3 = Hb[(size_t)j3 * 64 + lane];
            float w0 = __expf(fminf(leaky(a0 + adv), 60.f));
            float w1 = __expf(fminf(leaky(a1 + adv), 60.f));
            float w2 = __expf(fminf(leaky(a2 + adv), 60.f));
            float w3 = __expf(fminf(leaky(a3 + adv), 60.f));
            acc0 = fmaf(w0, bflo(v0), acc0); acc1 = fmaf(w0, bfhi(v0), acc1);
            acc0 = fmaf(w1, bflo(v1), acc0); acc1 = fmaf(w1, bfhi(v1), acc1);
            acc0 = fmaf(w2, bflo(v2), acc0); acc1 = fmaf(w2, bfhi(v2), acc1);
            acc0 = fmaf(w3, bflo(v3), acc0); acc1 = fmaf(w3, bfhi(v3), acc1);
            den += (w0 + w1) + (w2 + w3);
        }
        for (; t < cnt; ++t) {
            int j = __shfl(idx, t);
            float a = as1[j * 8 + h];
            unsigned int v = Hb[(size_t)j * 64 + lane];
            float w = __expf(fminf(leaky(a + adv), 60.f));
            acc0 = fmaf(w, bflo(v), acc0); acc1 = fmaf(w, bfhi(v), acc1);
            den += w;
        }
    }
    float r = 1.f / (den + 1e-16f);
    float2 bv = *(const float2*)(bias + 2 * lane);
    float o0 = acc0 * r + bv.x;
    float o1 = acc1 * r + bv.y;
    o0 = o0 > 0.f ? o0 : expm1f(o0);
    o1 = o1 > 0.f ? o1 : expm1f(o1);
    Hout[(size_t)i * 64 + lane] = (unsigned int)f2bf(o0) | ((unsigned int)f2bf(o1) << 16);
}

// ------------- layer-2 single-pass softmax-aggregate + bias + log_softmax -------------
__global__ __launch_bounds__(256) void k_agg2(const unsigned int* __restrict__ Hb,
                                              const float* __restrict__ as2,
                                              const float* __restrict__ ad2,
                                              const int* __restrict__ offs,
                                              const int* __restrict__ csr,
                                              const float* __restrict__ bias,
                                              float* __restrict__ out, int N)
{
    int i = (blockIdx.x * 256 + threadIdx.x) >> 6;
    int lane = threadIdx.x & 63;
    if (i >= N) return;
    const int half = lane >> 5, c = lane & 31;
    const int beg = offs[i], end = offs[i + 1];
    const float adv = ad2[i];

    float acc0 = 0.f, acc1 = 0.f, den = 0.f;
    for (int c0 = beg; c0 < end; c0 += 64) {
        int idxe = c0 + lane; if (idxe > end - 1) idxe = end - 1;
        int idx = csr[idxe];
        int cnt = end - c0; if (cnt > 64) cnt = 64;
        for (int t = 0; t < cnt; t += 2) {
            int tt = t + half;
            int tc2 = tt < cnt - 1 ? tt : cnt - 1;
            int j = __shfl(idx, tc2);
            float a = as2[j];
            unsigned int v = Hb[(size_t)j * 32 + c];
            float w = (tt < cnt) ? __expf(fminf(leaky(a + adv), 60.f)) : 0.f;
            acc0 = fmaf(w, bflo(v), acc0);
            acc1 = fmaf(w, bfhi(v), acc1);
            den += w;
        }
    }
    acc0 += __shfl_xor(acc0, 32);
    acc1 += __shfl_xor(acc1, 32);
    den  += __shfl_xor(den, 32);

    float r = 1.f / (den + 1e-16f);
    float2 bv = *(const float2*)(bias + 2 * c);
    float o0 = acc0 * r + bv.x;
    float o1 = acc1 * r + bv.y;
    float mx = fmaxf(o0, o1);
#pragma unroll
    for (int k = 1; k < 32; k <<= 1) mx = fmaxf(mx, __shfl_xor(mx, k));
    float s = __expf(o0 - mx) + __expf(o1 - mx);
#pragma unroll
    for (int k = 1; k < 32; k <<= 1) s += __shfl_xor(s, k);
    float ls = __logf(s);
    if (half == 0) {
        float2 o = {(o0 - mx) - ls, (o1 - mx) - ls};
        *(float2*)(out + (size_t)i * OUT_CH + 2 * c) = o;
    }
}

extern "C" void kernel_launch(void* const* d_in, const int* in_sizes, int n_in,
                              void* d_out, int out_size, void* d_ws, size_t ws_size,
                              hipStream_t stream)
{
    const float* x    = (const float*)d_in[0];
    const int*   ei   = (const int*)  d_in[1];
    const float* W1   = (const float*)d_in[2];
    const float* atS1 = (const float*)d_in[3];
    const float* atD1 = (const float*)d_in[4];
    const float* b1   = (const float*)d_in[5];
    const float* W2   = (const float*)d_in[6];
    const float* atS2 = (const float*)d_in[7];
    const float* atD2 = (const float*)d_in[8];
    const float* b2   = (const float*)d_in[9];
    float* out = (float*)d_out;

    const int N  = in_sizes[0] / IN_C;
    const int E  = in_sizes[1] / 2;
    const int NE = E + N;

    // ---- workspace layout ----
    char* p = (char*)d_ws;
    unsigned short* h1b  = (unsigned short*)p; p += (size_t)N * C1 * 2;      // bf16 [N,128]
    unsigned short* h2in = (unsigned short*)p; p += (size_t)N * C1 * 2;      // bf16 [N,128]
    unsigned short* h2b  = (unsigned short*)p; p += (size_t)N * OUT_CH * 2;  // bf16 [N,64]
    unsigned short* Wt1  = (unsigned short*)p; p += (size_t)128 * 256 * 2;
    unsigned short* Wt2  = (unsigned short*)p; p += (size_t)64 * 128 * 2;
    float* as1  = (float*)p;                  p += (size_t)N * 8 * 4;
    float* ad1  = (float*)p;                  p += (size_t)N * 8 * 4;
    float* as2  = (float*)p;                  p += (size_t)N * 4;
    float* ad2  = (float*)p;                  p += (size_t)N * 4;
    int* counts = (int*)p;                    p += (size_t)N * 4;
    int* offs   = (int*)p;                    p += (size_t)(N + 1) * 4;
    int* bsums  = (int*)p;                    p += 1024 * 4;
    int* rank   = (int*)p;                    p += (size_t)NE * 4;
    int* csr    = (int*)p;                    p += (size_t)NE * 4;

    const int nblk = (N + 1023) / 1024;

    hipMemsetAsync(counts, 0, sizeof(int) * (size_t)N, stream);

    // weight prep (bf16 transpose)
    k_prep<<<(256 * 128 + 128 * 64 + 255) / 256, 256, 0, stream>>>(W1, W2, Wt1, Wt2);

    // layer 1 GEMM (MFMA) + fused logits
    k_gemm1<<<(N + 63) / 64, 256, 0, stream>>>(x, Wt1, atS1, atD1, h1b, as1, ad1, N);

    // CSR build
    k_hist<<<(NE + 255) / 256, 256, 0, stream>>>(ei, counts, rank, E, NE);
    k_bsum<<<nblk, 1024, 0, stream>>>(counts, bsums, N);
    k_scan_bsums<<<1, 1024, 0, stream>>>(bsums, offs, nblk, NE, N);
    k_scan_final<<<nblk, 1024, 0, stream>>>(counts, bsums, offs, N);
    k_scatter<<<(NE + 255) / 256, 256, 0, stream>>>(ei, offs, rank, csr, E, NE);

    // layer 1 aggregate (+bias+ELU) -> bf16
    k_agg1<<<(N + 3) / 4, 256, 0, stream>>>((const unsigned int*)h1b, as1, ad1, offs, csr, b1,
                                            (unsigned int*)h2in, N);

    // layer 2 GEMM (MFMA) + fused logits, then aggregate
    k_gemm2<<<(N + 63) / 64, 256, 0, stream>>>(h2in, Wt2, atS2, atD2, h2b, as2, ad2, N);
    k_agg2<<<(N + 3) / 4, 256, 0, stream>>>((const unsigned int*)h2b, as2, ad2, offs, csr, b2, out, N);
}

// Round 5
// 302.990 us; speedup vs baseline: 3.0681x; 1.0815x over previous
//
#include <hip/hip_runtime.h>
#include <hip/hip_bf16.h>

#define IN_C 256
#define C1   128   // HEADS*HID
#define OUT_CH 64
#define NEG 0.2f
#define STR 40     // LDS row stride in shorts (80B): 16B-aligned, conflict-free b128

typedef __attribute__((ext_vector_type(8))) short bf16x8;
typedef __attribute__((ext_vector_type(4))) float f32x4;

__device__ __forceinline__ float leaky(float x) { return x > 0.f ? x : NEG * x; }
__device__ __forceinline__ unsigned short f2bf(float f) {
    unsigned int x = __float_as_uint(f);
    unsigned int r = (x + 0x7fffu + ((x >> 16) & 1u)) >> 16;   // RNE
    return (unsigned short)r;
}
__device__ __forceinline__ float bflo(unsigned int v) { return __uint_as_float(v << 16); }
__device__ __forceinline__ float bfhi(unsigned int v) { return __uint_as_float(v & 0xffff0000u); }

// ---- one-time weight transpose+cast: Wt1[n][k] bf16, Wt2[n][k] bf16 ----
__global__ __launch_bounds__(256) void k_prep(const float* __restrict__ W1,
                                              const float* __restrict__ W2,
                                              unsigned short* __restrict__ Wt1,
                                              unsigned short* __restrict__ Wt2)
{
    int t = blockIdx.x * 256 + threadIdx.x;
    if (t < 256 * 128) {
        int k = t >> 7, n = t & 127;
        Wt1[n * 256 + k] = f2bf(W1[t]);
    } else {
        int q = t - 256 * 128;
        if (q < 128 * 64) {
            int k = q >> 6, n = q & 63;
            Wt2[n * 128 + k] = f2bf(W2[q]);
        }
    }
}

// ---- GEMM1 (MFMA bf16): [M,256]f32 x Wt1 -> bf16 [M,128] + fused att1 logits ----
__global__ __launch_bounds__(256) void k_gemm1(const float* __restrict__ X,
                                               const unsigned short* __restrict__ Wt1,
                                               const float* __restrict__ atts,
                                               const float* __restrict__ attd,
                                               unsigned short* __restrict__ Hb,
                                               float* __restrict__ as1,
                                               float* __restrict__ ad1, int M)
{
    __shared__ unsigned short As[64 * STR];
    __shared__ unsigned short Bs[128 * STR];
    const int tid = threadIdx.x;
    const int w = tid >> 6, lane = tid & 63;
    const int l15 = lane & 15, kg = lane >> 4;
    const int rowBase = blockIdx.x * 64;

    f32x4 acc[8];
#pragma unroll
    for (int i = 0; i < 8; ++i) acc[i] = (f32x4){0.f, 0.f, 0.f, 0.f};

    for (int k0 = 0; k0 < 256; k0 += 32) {
        {
            int row = tid >> 2, ko = (tid & 3) * 8;
            int r = rowBase + row; if (r > M - 1) r = M - 1;
            const float* src = X + (size_t)r * IN_C + k0 + ko;
            float4 f0 = *(const float4*)src;
            float4 f1 = *(const float4*)(src + 4);
            uint4 pk;
            pk.x = (unsigned int)f2bf(f0.x) | ((unsigned int)f2bf(f0.y) << 16);
            pk.y = (unsigned int)f2bf(f0.z) | ((unsigned int)f2bf(f0.w) << 16);
            pk.z = (unsigned int)f2bf(f1.x) | ((unsigned int)f2bf(f1.y) << 16);
            pk.w = (unsigned int)f2bf(f1.z) | ((unsigned int)f2bf(f1.w) << 16);
            *(uint4*)(&As[row * STR + ko]) = pk;
        }
        {
            int n = tid >> 1, ko = (tid & 1) * 16;
            const unsigned short* src = Wt1 + n * 256 + k0 + ko;
            uint4 b0 = *(const uint4*)src;
            uint4 b1 = *(const uint4*)(src + 8);
            *(uint4*)(&Bs[n * STR + ko]) = b0;
            *(uint4*)(&Bs[n * STR + ko + 8]) = b1;
        }
        __syncthreads();
        bf16x8 a = *(const bf16x8*)(&As[(w * 16 + l15) * STR + kg * 8]);
#pragma unroll
        for (int i = 0; i < 8; ++i) {
            bf16x8 b = *(const bf16x8*)(&Bs[(i * 16 + l15) * STR + kg * 8]);
            acc[i] = __builtin_amdgcn_mfma_f32_16x16x32_bf16(a, b, acc[i], 0, 0, 0);
        }
        __syncthreads();
    }

    float avs[8], avd[8];
#pragma unroll
    for (int i = 0; i < 8; ++i) {
        avs[i] = atts[i * 16 + l15];
        avd[i] = attd[i * 16 + l15];
    }
#pragma unroll
    for (int r = 0; r < 4; ++r) {
        int row = rowBase + w * 16 + 4 * kg + r;
        bool ok = row < M;
#pragma unroll
        for (int i = 0; i < 8; ++i) {
            float v = acc[i][r];
            if (ok) Hb[(size_t)row * C1 + i * 16 + l15] = f2bf(v);
            float s = v * avs[i];
            float d = v * avd[i];
            s += __shfl_xor(s, 1); s += __shfl_xor(s, 2);
            s += __shfl_xor(s, 4); s += __shfl_xor(s, 8);
            d += __shfl_xor(d, 1); d += __shfl_xor(d, 2);
            d += __shfl_xor(d, 4); d += __shfl_xor(d, 8);
            if (ok && l15 == 0) { as1[row * 8 + i] = s; ad1[row * 8 + i] = d; }
        }
    }
}

// ---- GEMM2 (MFMA bf16): [M,128]bf16 x Wt2 -> bf16 [M,64] + fused att2 logits ----
__global__ __launch_bounds__(256) void k_gemm2(const unsigned short* __restrict__ Xb,
                                               const unsigned short* __restrict__ Wt2,
                                               const float* __restrict__ atts,
                                               const float* __restrict__ attd,
                                               unsigned short* __restrict__ Hb,
                                               float* __restrict__ as2,
                                               float* __restrict__ ad2, int M)
{
    __shared__ unsigned short As[64 * STR];
    __shared__ unsigned short Bs[64 * STR];
    const int tid = threadIdx.x;
    const int w = tid >> 6, lane = tid & 63;
    const int l15 = lane & 15, kg = lane >> 4;
    const int rowBase = blockIdx.x * 64;

    f32x4 acc[4];
#pragma unroll
    for (int i = 0; i < 4; ++i) acc[i] = (f32x4){0.f, 0.f, 0.f, 0.f};

    for (int k0 = 0; k0 < 128; k0 += 32) {
        {
            int row = tid >> 2, ko = (tid & 3) * 8;
            int r = rowBase + row; if (r > M - 1) r = M - 1;
            uint4 v = *(const uint4*)(Xb + (size_t)r * C1 + k0 + ko);
            *(uint4*)(&As[row * STR + ko]) = v;
        }
        {
            int n = tid >> 2, ko = (tid & 3) * 8;
            uint4 v = *(const uint4*)(Wt2 + n * 128 + k0 + ko);
            *(uint4*)(&Bs[n * STR + ko]) = v;
        }
        __syncthreads();
        bf16x8 a = *(const bf16x8*)(&As[(w * 16 + l15) * STR + kg * 8]);
#pragma unroll
        for (int i = 0; i < 4; ++i) {
            bf16x8 b = *(const bf16x8*)(&Bs[(i * 16 + l15) * STR + kg * 8]);
            acc[i] = __builtin_amdgcn_mfma_f32_16x16x32_bf16(a, b, acc[i], 0, 0, 0);
        }
        __syncthreads();
    }

    float avs[4], avd[4];
#pragma unroll
    for (int i = 0; i < 4; ++i) {
        avs[i] = atts[i * 16 + l15];
        avd[i] = attd[i * 16 + l15];
    }
#pragma unroll
    for (int r = 0; r < 4; ++r) {
        int row = rowBase + w * 16 + 4 * kg + r;
        bool ok = row < M;
        float s = 0.f, d = 0.f;
#pragma unroll
        for (int i = 0; i < 4; ++i) {
            float v = acc[i][r];
            if (ok) Hb[(size_t)row * OUT_CH + i * 16 + l15] = f2bf(v);
            s = fmaf(v, avs[i], s);
            d = fmaf(v, avd[i], d);
        }
        s += __shfl_xor(s, 1); s += __shfl_xor(s, 2);
        s += __shfl_xor(s, 4); s += __shfl_xor(s, 8);
        d += __shfl_xor(d, 1); d += __shfl_xor(d, 2);
        d += __shfl_xor(d, 4); d += __shfl_xor(d, 8);
        if (ok && l15 == 0) { as2[row] = s; ad2[row] = d; }
    }
}

// ---------------- CSR build ----------------
__global__ void k_hist(const int* __restrict__ ei, int* __restrict__ counts,
                       int* __restrict__ rank, int E, int NE)
{
    int e = blockIdx.x * blockDim.x + threadIdx.x;
    if (e >= NE) return;
    int d = (e < E) ? ei[E + e] : (e - E);
    rank[e] = atomicAdd(&counts[d], 1);
}

__global__ __launch_bounds__(1024) void k_bsum(const int* __restrict__ counts,
                                               int* __restrict__ bsums, int n)
{
    __shared__ int sm[1024];
    int tid = threadIdx.x;
    int i = blockIdx.x * 1024 + tid;
    sm[tid] = (i < n) ? counts[i] : 0;
    __syncthreads();
    for (int s = 512; s > 0; s >>= 1) {
        if (tid < s) sm[tid] += sm[tid + s];
        __syncthreads();
    }
    if (tid == 0) bsums[blockIdx.x] = sm[0];
}

__global__ __launch_bounds__(1024) void k_scan_bsums(int* __restrict__ bsums,
                                                     int* __restrict__ offs,
                                                     int nblk, int total, int n)
{
    __shared__ int sm[1024];
    int tid = threadIdx.x;
    int val = (tid < nblk) ? bsums[tid] : 0;
    sm[tid] = val;
    __syncthreads();
    for (int off = 1; off < 1024; off <<= 1) {
        int t = (tid >= off) ? sm[tid - off] : 0;
        __syncthreads();
        sm[tid] += t;
        __syncthreads();
    }
    if (tid < nblk) bsums[tid] = sm[tid] - val;
    if (tid == 0) offs[n] = total;
}

__global__ __launch_bounds__(1024) void k_scan_final(const int* __restrict__ counts,
                                                     const int* __restrict__ bsums,
                                                     int* __restrict__ offs, int n)
{
    __shared__ int sm[1024];
    int tid = threadIdx.x;
    int i = blockIdx.x * 1024 + tid;
    int v = (i < n) ? counts[i] : 0;
    sm[tid] = v;
    __syncthreads();
    for (int off = 1; off < 1024; off <<= 1) {
        int t = (tid >= off) ? sm[tid - off] : 0;
        __syncthreads();
        sm[tid] += t;
        __syncthreads();
    }
    if (i < n) offs[i] = bsums[blockIdx.x] + sm[tid] - v;
}

__global__ void k_scatter(const int* __restrict__ ei, const int* __restrict__ offs,
                          const int* __restrict__ rank, int* __restrict__ csr, int E, int NE)
{
    int e = blockIdx.x * blockDim.x + threadIdx.x;
    if (e >= NE) return;
    int s, d;
    if (e < E) { s = ei[e]; d = ei[E + e]; } else { s = d = e - E; }
    csr[offs[d] + rank[e]] = s;
}

// ------------- layer-1 softmax-aggregate + bias + ELU -> bf16 -------------
// One wave per dst node; 4 edges processed per wave-iteration.
// Lane (sub=lane>>4, l16=lane&15) owns channels 8*l16..8*l16+7 (head l16>>1) of edge sub.
__global__ __launch_bounds__(256) void k_agg1(const unsigned short* __restrict__ Hb,
                                              const float* __restrict__ as1,
                                              const float* __restrict__ ad1,
                                              const int* __restrict__ offs,
                                              const int* __restrict__ csr,
                                              const float* __restrict__ bias,
                                              unsigned int* __restrict__ Hout, int N)
{
    int i = (blockIdx.x * 256 + threadIdx.x) >> 6;
    int lane = threadIdx.x & 63;
    if (i >= N) return;
    const int sub = lane >> 4, l16 = lane & 15;
    const int head = l16 >> 1;
    const int beg = offs[i], end = offs[i + 1];
    const float adv = ad1[i * 8 + head];

    float acc[8];
#pragma unroll
    for (int k = 0; k < 8; ++k) acc[k] = 0.f;
    float den = 0.f;

    for (int c0 = beg; c0 < end; c0 += 64) {
        int idxe = c0 + lane; if (idxe > end - 1) idxe = end - 1;
        int idx = csr[idxe];
        int cnt = end - c0; if (cnt > 64) cnt = 64;
        int nt = (cnt + 3) >> 2;
        for (int t = 0; t < nt; ++t) {
            int sl = t * 4 + sub;
            int j = __shfl(idx, sl);
            float a = as1[j * 8 + head];
            const uint4 v = *(const uint4*)(Hb + (size_t)j * C1 + l16 * 8);
            float w = __expf(fminf(leaky(a + adv), 60.f));
            w = (sl < cnt) ? w : 0.f;
            acc[0] = fmaf(w, bflo(v.x), acc[0]); acc[1] = fmaf(w, bfhi(v.x), acc[1]);
            acc[2] = fmaf(w, bflo(v.y), acc[2]); acc[3] = fmaf(w, bfhi(v.y), acc[3]);
            acc[4] = fmaf(w, bflo(v.z), acc[4]); acc[5] = fmaf(w, bfhi(v.z), acc[5]);
            acc[6] = fmaf(w, bflo(v.w), acc[6]); acc[7] = fmaf(w, bfhi(v.w), acc[7]);
            den += w;
        }
    }
    // combine the 4 sub-groups (lane bits 4,5)
#pragma unroll
    for (int k = 0; k < 8; ++k) {
        acc[k] += __shfl_xor(acc[k], 16);
        acc[k] += __shfl_xor(acc[k], 32);
    }
    den += __shfl_xor(den, 16);
    den += __shfl_xor(den, 32);

    float r = 1.f / (den + 1e-16f);
    // lane (sub,l16) outputs channel pair (8*l16 + 2*sub, +1) -> static acc selection
    float a0 = sub == 0 ? acc[0] : sub == 1 ? acc[2] : sub == 2 ? acc[4] : acc[6];
    float a1 = sub == 0 ? acc[1] : sub == 1 ? acc[3] : sub == 2 ? acc[5] : acc[7];
    int ci = 4 * l16 + sub;                       // uint index within row
    float2 bv = *(const float2*)(bias + 2 * ci);
    float o0 = a0 * r + bv.x;
    float o1 = a1 * r + bv.y;
    o0 = o0 > 0.f ? o0 : __expf(o0) - 1.f;
    o1 = o1 > 0.f ? o1 : __expf(o1) - 1.f;
    Hout[(size_t)i * 64 + ci] = (unsigned int)f2bf(o0) | ((unsigned int)f2bf(o1) << 16);
}

// ------------- layer-2 softmax-aggregate + bias + log_softmax -------------
// One wave per dst node; 8 edges per wave-iteration.
// Lane (sub=lane>>3, l8=lane&7) owns channels 8*l8..8*l8+7 of edge sub.
__global__ __launch_bounds__(256) void k_agg2(const unsigned short* __restrict__ Hb,
                                              const float* __restrict__ as2,
                                              const float* __restrict__ ad2,
                                              const int* __restrict__ offs,
                                              const int* __restrict__ csr,
                                              const float* __restrict__ bias,
                                              float* __restrict__ out, int N)
{
    int i = (blockIdx.x * 256 + threadIdx.x) >> 6;
    int lane = threadIdx.x & 63;
    if (i >= N) return;
    const int sub = lane >> 3, l8 = lane & 7;
    const int beg = offs[i], end = offs[i + 1];
    const float adv = ad2[i];

    float acc[8];
#pragma unroll
    for (int k = 0; k < 8; ++k) acc[k] = 0.f;
    float den = 0.f;

    for (int c0 = beg; c0 < end; c0 += 64) {
        int idxe = c0 + lane; if (idxe > end - 1) idxe = end - 1;
        int idx = csr[idxe];
        int cnt = end - c0; if (cnt > 64) cnt = 64;
        int nt = (cnt + 7) >> 3;
        for (int t = 0; t < nt; ++t) {
            int sl = t * 8 + sub;
            int j = __shfl(idx, sl);
            float a = as2[j];
            const uint4 v = *(const uint4*)(Hb + (size_t)j * OUT_CH + l8 * 8);
            float w = __expf(fminf(leaky(a + adv), 60.f));
            w = (sl < cnt) ? w : 0.f;
            acc[0] = fmaf(w, bflo(v.x), acc[0]); acc[1] = fmaf(w, bfhi(v.x), acc[1]);
            acc[2] = fmaf(w, bflo(v.y), acc[2]); acc[3] = fmaf(w, bfhi(v.y), acc[3]);
            acc[4] = fmaf(w, bflo(v.z), acc[4]); acc[5] = fmaf(w, bfhi(v.z), acc[5]);
            acc[6] = fmaf(w, bflo(v.w), acc[6]); acc[7] = fmaf(w, bfhi(v.w), acc[7]);
            den += w;
        }
    }
    // combine the 8 sub-groups (lane bits 3,4,5)
#pragma unroll
    for (int k = 0; k < 8; ++k) {
        acc[k] += __shfl_xor(acc[k], 8);
        acc[k] += __shfl_xor(acc[k], 16);
        acc[k] += __shfl_xor(acc[k], 32);
    }
    den += __shfl_xor(den, 8);
    den += __shfl_xor(den, 16);
    den += __shfl_xor(den, 32);

    float r = 1.f / (den + 1e-16f);
    // lane (sub,l8) outputs channel c = 8*l8 + sub = acc[sub] (static selection chain)
    float av = sub == 0 ? acc[0] : sub == 1 ? acc[1] : sub == 2 ? acc[2] : sub == 3 ? acc[3]
             : sub == 4 ? acc[4] : sub == 5 ? acc[5] : sub == 6 ? acc[6] : acc[7];
    int c = 8 * l8 + sub;
    float o = av * r + bias[c];
    // log_softmax over the 64 channels (one per lane, arbitrary bijection)
    float mx = o;
#pragma unroll
    for (int k = 1; k < 64; k <<= 1) mx = fmaxf(mx, __shfl_xor(mx, k));
    float ex = __expf(o - mx), s = ex;
#pragma unroll
    for (int k = 1; k < 64; k <<= 1) s += __shfl_xor(s, k);
    out[(size_t)i * OUT_CH + c] = (o - mx) - __logf(s);
}

extern "C" void kernel_launch(void* const* d_in, const int* in_sizes, int n_in,
                              void* d_out, int out_size, void* d_ws, size_t ws_size,
                              hipStream_t stream)
{
    const float* x    = (const float*)d_in[0];
    const int*   ei   = (const int*)  d_in[1];
    const float* W1   = (const float*)d_in[2];
    const float* atS1 = (const float*)d_in[3];
    const float* atD1 = (const float*)d_in[4];
    const float* b1   = (const float*)d_in[5];
    const float* W2   = (const float*)d_in[6];
    const float* atS2 = (const float*)d_in[7];
    const float* atD2 = (const float*)d_in[8];
    const float* b2   = (const float*)d_in[9];
    float* out = (float*)d_out;

    const int N  = in_sizes[0] / IN_C;
    const int E  = in_sizes[1] / 2;
    const int NE = E + N;

    // ---- workspace layout ----
    char* p = (char*)d_ws;
    unsigned short* h1b  = (unsigned short*)p; p += (size_t)N * C1 * 2;      // bf16 [N,128]
    unsigned short* h2in = (unsigned short*)p; p += (size_t)N * C1 * 2;      // bf16 [N,128]
    unsigned short* h2b  = (unsigned short*)p; p += (size_t)N * OUT_CH * 2;  // bf16 [N,64]
    unsigned short* Wt1  = (unsigned short*)p; p += (size_t)128 * 256 * 2;
    unsigned short* Wt2  = (unsigned short*)p; p += (size_t)64 * 128 * 2;
    float* as1  = (float*)p;                  p += (size_t)N * 8 * 4;
    float* ad1  = (float*)p;                  p += (size_t)N * 8 * 4;
    float* as2  = (float*)p;                  p += (size_t)N * 4;
    float* ad2  = (float*)p;                  p += (size_t)N * 4;
    int* counts = (int*)p;                    p += (size_t)N * 4;
    int* offs   = (int*)p;                    p += (size_t)(N + 1) * 4;
    int* bsums  = (int*)p;                    p += 1024 * 4;
    int* rank   = (int*)p;                    p += (size_t)NE * 4;
    int* csr    = (int*)p;                    p += (size_t)NE * 4;

    const int nblk = (N + 1023) / 1024;

    hipMemsetAsync(counts, 0, sizeof(int) * (size_t)N, stream);

    // weight prep (bf16 transpose)
    k_prep<<<(256 * 128 + 128 * 64 + 255) / 256, 256, 0, stream>>>(W1, W2, Wt1, Wt2);

    // layer 1 GEMM (MFMA) + fused logits
    k_gemm1<<<(N + 63) / 64, 256, 0, stream>>>(x, Wt1, atS1, atD1, h1b, as1, ad1, N);

    // CSR build
    k_hist<<<(NE + 255) / 256, 256, 0, stream>>>(ei, counts, rank, E, NE);
    k_bsum<<<nblk, 1024, 0, stream>>>(counts, bsums, N);
    k_scan_bsums<<<1, 1024, 0, stream>>>(bsums, offs, nblk, NE, N);
    k_scan_final<<<nblk, 1024, 0, stream>>>(counts, bsums, offs, N);
    k_scatter<<<(NE + 255) / 256, 256, 0, stream>>>(ei, offs, rank, csr, E, NE);

    // layer 1 aggregate (+bias+ELU) -> bf16
    k_agg1<<<(N + 3) / 4, 256, 0, stream>>>(h1b, as1, ad1, offs, csr, b1,
                                            (unsigned int*)h2in, N);

    // layer 2 GEMM (MFMA) + fused logits, then aggregate
    k_gemm2<<<(N + 63) / 64, 256, 0, stream>>>(h2in, Wt2, atS2, atD2, h2b, as2, ad2, N);
    k_agg2<<<(N + 3) / 4, 256, 0, stream>>>(h2b, as2, ad2, offs, csr, b2, out, N);
}